// Round 3
// baseline (15315.764 us; speedup 1.0000x reference)
//
#include <hip/hip_runtime.h>
#include <cstddef>

// ---------------- problem constants ----------------
constexpr int NA   = 100000;
constexpr int NE   = 200000;
constexpr int NN2  = 200000;
constexpr int NASS = 400000;
constexpr int NE2  = 400000;
constexpr int NG   = 5000;
constexpr int D    = 256;
constexpr int FEAT = 40;
constexpr int NI2  = 8;
constexpr int NL   = 5;
constexpr int CH   = 25000;   // GIN MLP row chunk (NA = 4*CH)
constexpr int XCH  = 72000;   // xp f32 accumulation chunk rows (3 passes)
constexpr int OCH  = 34000;   // conv f32 accumulation chunk rows (6 passes)

typedef unsigned short u16;

static __device__ __forceinline__ float b2f(u16 s) {
    union { unsigned int u; float f; } v; v.u = ((unsigned int)s) << 16; return v.f;
}
static __device__ __forceinline__ u16 f2b(float f) {
    union { unsigned int u; float f; } v; v.f = f;
    unsigned int r = v.u + 0x7FFFu + ((v.u >> 16) & 1u);
    return (u16)(r >> 16);
}

// ---------------- workspace layout (byte offsets), ws_size = 240 MiB ----------------
// live-range audit:
//  GIN:    Z f32[NA,D] @0..102.4M | HB bf16[NA,D] @102.4..153.6M | TC f32[CH,2D] @153.6..204.8M
//  xp:     XPB bf16[NN2,D] @0..102.4M (Z dead) | HB live | XPC f32[XCH,D] @153.6..227.3M (TC dead)
//  conv1:  XPB live | HN bf16[NN2,D] @102.4..204.8M (HB,XPC dead) | OC f32[OCH,D] @204.8..239.6M
//          X2B overwrites XPB chunk-in-place
//  conv2:  X2B @0.. | HN2 reuses HN region | OC reused; x2 pooled directly from OC
//  head:   F1/F2/F3 @102.4M.. (HN2 dead)
//  tail @240,000,000: Mb[NG,2D] f32, CG[NG], CN2[NN2], CG2[NG], BS/BQ/SC/SH[D]
constexpr size_t Z_OFF   = 0;
constexpr size_t HB_OFF  = 102400000;
constexpr size_t TC_OFF  = 153600000;
constexpr size_t XPB_OFF = 0;
constexpr size_t XPC_OFF = 153600000;
constexpr size_t HN_OFF  = 102400000;
constexpr size_t OC_OFF  = 204800000;
constexpr size_t F1_OFF  = 102400000;
constexpr size_t F2_OFF  = F1_OFF + (size_t)NG * D * 4;
constexpr size_t F3_OFF  = F2_OFF + (size_t)NG * (D / 2) * 4;
constexpr size_t TAIL    = 240000000;
constexpr size_t MB_OFF  = TAIL;
constexpr size_t CG_OFF  = MB_OFF  + (size_t)NG * 2 * D * 4;   // +10,240,000
constexpr size_t CN2_OFF = CG_OFF  + (size_t)NG * 4;
constexpr size_t CG2_OFF = CN2_OFF + (size_t)NN2 * 4;
constexpr size_t BS_OFF  = CG2_OFF + (size_t)NG * 4;
constexpr size_t BQ_OFF  = BS_OFF + D * 4;
constexpr size_t SC_OFF  = BQ_OFF + D * 4;
constexpr size_t SH_OFF  = SC_OFF + D * 4;
constexpr size_t WS_BYTES= SH_OFF + D * 4;   // 251,084,096 <= 251,658,240

// ---------------- generic tiled GEMM, A/C optionally bf16 ----------------
template<int ABF, int CBF>
__global__ __launch_bounds__(256) void k_gemm(
    const void* __restrict__ Av, int lda,
    const float* __restrict__ B, int ldb,
    const float* __restrict__ bias,
    void* __restrict__ Cv, int ldc,
    int M, int N, int K, int relu, int acc)
{
    __shared__ __align__(16) float As[16][68];
    __shared__ __align__(16) float Bs[16][68];
    const int tid = threadIdx.x;
    const int tx = tid & 15, ty = tid >> 4;
    const int bm = blockIdx.y * 64;
    const int bn = blockIdx.x * 64;
    const int arow = tid >> 2;
    const int akq  = (tid & 3) << 2;
    const int bk   = tid >> 4;
    const int bnq  = (tid & 15) << 2;
    float c[4][4] = {};
    const int ktiles = (K + 15) >> 4;
    for (int kt = 0; kt < ktiles; ++kt) {
        const int k0 = kt << 4;
        float4 av = make_float4(0.f, 0.f, 0.f, 0.f);
        if (bm + arow < M && k0 + akq + 4 <= K) {
            if (ABF) {
                const u16* A = (const u16*)Av;
                ushort4 u = *reinterpret_cast<const ushort4*>(A + (size_t)(bm + arow) * lda + (k0 + akq));
                av = make_float4(b2f(u.x), b2f(u.y), b2f(u.z), b2f(u.w));
            } else {
                const float* A = (const float*)Av;
                av = *reinterpret_cast<const float4*>(A + (size_t)(bm + arow) * lda + (k0 + akq));
            }
        }
        As[akq + 0][arow] = av.x;
        As[akq + 1][arow] = av.y;
        As[akq + 2][arow] = av.z;
        As[akq + 3][arow] = av.w;
        float4 bv = make_float4(0.f, 0.f, 0.f, 0.f);
        if (k0 + bk < K && bn + bnq + 4 <= N)
            bv = *reinterpret_cast<const float4*>(B + (size_t)(k0 + bk) * ldb + (bn + bnq));
        *reinterpret_cast<float4*>(&Bs[bk][bnq]) = bv;
        __syncthreads();
        #pragma unroll
        for (int k = 0; k < 16; ++k) {
            float a0 = As[k][ty * 4 + 0], a1 = As[k][ty * 4 + 1];
            float a2 = As[k][ty * 4 + 2], a3 = As[k][ty * 4 + 3];
            float b0 = Bs[k][tx * 4 + 0], b1 = Bs[k][tx * 4 + 1];
            float b2 = Bs[k][tx * 4 + 2], b3 = Bs[k][tx * 4 + 3];
            c[0][0] += a0 * b0; c[0][1] += a0 * b1; c[0][2] += a0 * b2; c[0][3] += a0 * b3;
            c[1][0] += a1 * b0; c[1][1] += a1 * b1; c[1][2] += a1 * b2; c[1][3] += a1 * b3;
            c[2][0] += a2 * b0; c[2][1] += a2 * b1; c[2][2] += a2 * b2; c[2][3] += a2 * b3;
            c[3][0] += a3 * b0; c[3][1] += a3 * b1; c[3][2] += a3 * b2; c[3][3] += a3 * b3;
        }
        __syncthreads();
    }
    #pragma unroll
    for (int i = 0; i < 4; ++i) {
        int row = bm + ty * 4 + i;
        if (row >= M) continue;
        #pragma unroll
        for (int j = 0; j < 4; ++j) {
            int col = bn + tx * 4 + j;
            if (col >= N) continue;
            size_t idx = (size_t)row * ldc + col;
            float v = c[i][j];
            if (bias) v += bias[col];
            if (acc)  v += CBF ? b2f(((const u16*)Cv)[idx]) : ((const float*)Cv)[idx];
            if (relu) v = fmaxf(v, 0.f);
            if (CBF) ((u16*)Cv)[idx] = f2b(v); else ((float*)Cv)[idx] = v;
        }
    }
}

// ---------------- elementwise / scatter kernels ----------------
__global__ void k_zero(float* __restrict__ p, size_t n) {
    size_t i = (size_t)blockIdx.x * blockDim.x + threadIdx.x;
    size_t st = (size_t)gridDim.x * blockDim.x;
    for (; i < n; i += st) p[i] = 0.f;
}

__global__ void k_fill(float* __restrict__ p, int n, float v) {
    int i = blockIdx.x * blockDim.x + threadIdx.x;
    int st = gridDim.x * blockDim.x;
    for (; i < n; i += st) p[i] = v;
}

// Z = (1+eps[l]) * h
__global__ void k_scale(float* __restrict__ z, const u16* __restrict__ h,
                        const float* __restrict__ epsv, int l, size_t n) {
    float f = 1.0f + epsv[l];
    size_t i = (size_t)blockIdx.x * blockDim.x + threadIdx.x;
    size_t st = (size_t)gridDim.x * blockDim.x;
    for (; i < n; i += st) z[i] = f * b2f(h[i]);
}

// wave-per-entry: Z[dst] += h[src] + tbl[attr]
__global__ void k_edge_gin(const u16* __restrict__ h, const float* __restrict__ tbl,
                           const int* __restrict__ src, const int* __restrict__ dst,
                           const int* __restrict__ attr, float* __restrict__ z, int ne) {
    int wid = (blockIdx.x * blockDim.x + threadIdx.x) >> 6;
    int lane = threadIdx.x & 63;
    int nw = (gridDim.x * blockDim.x) >> 6;
    int c = lane * 4;
    for (int e = wid; e < ne; e += nw) {
        int s = src[e], d = dst[e], a = attr[e];
        ushort4 u = *reinterpret_cast<const ushort4*>(h + (size_t)s * D + c);
        float4 t = *reinterpret_cast<const float4*>(tbl + (size_t)a * D + c);
        float* zp = z + (size_t)d * D + c;
        atomicAdd(zp + 0, b2f(u.x) + t.x);
        atomicAdd(zp + 1, b2f(u.y) + t.y);
        atomicAdd(zp + 2, b2f(u.z) + t.z);
        atomicAdd(zp + 3, b2f(u.w) + t.w);
    }
}

__global__ void k_bn_stats(const u16* __restrict__ z, float* __restrict__ sum,
                           float* __restrict__ sumsq, int n) {
    int c = threadIdx.x;
    float s = 0.f, q = 0.f;
    for (int r = blockIdx.x; r < n; r += gridDim.x) {
        float v = b2f(z[(size_t)r * D + c]);
        s += v; q += v * v;
    }
    atomicAdd(&sum[c], s);
    atomicAdd(&sumsq[c], q);
}

__global__ void k_bn_final(const float* __restrict__ sum, const float* __restrict__ sumsq,
                           const float* __restrict__ gamma, const float* __restrict__ beta,
                           float* __restrict__ scale, float* __restrict__ shift, int n) {
    int c = threadIdx.x;
    float mu  = sum[c] / (float)n;
    float var = sumsq[c] / (float)n - mu * mu;
    float sc  = gamma[c] * rsqrtf(var + 1e-5f);
    scale[c] = sc;
    shift[c] = beta[c] - mu * sc;
}

__global__ void k_bn_apply(u16* __restrict__ h, const float* __restrict__ scale,
                           const float* __restrict__ shift, size_t n, int relu) {
    size_t i = (size_t)blockIdx.x * blockDim.x + threadIdx.x;
    size_t st = (size_t)gridDim.x * blockDim.x;
    for (; i < n; i += st) {
        int c = (int)(i & (D - 1));
        float v = scale[c] * b2f(h[i]) + shift[c];
        if (relu) v = fmaxf(v, 0.f);
        h[i] = f2b(v);
    }
}

// x1 pool: Mb[batch[r], 0:D] += HB[r]; CG[batch[r]] += 1
__global__ void k_pool1(float* __restrict__ mb, const u16* __restrict__ hb,
                        const int* __restrict__ batch, float* __restrict__ cg, int n) {
    int wid = (blockIdx.x * blockDim.x + threadIdx.x) >> 6;
    int lane = threadIdx.x & 63;
    int nw = (gridDim.x * blockDim.x) >> 6;
    int c = lane * 4;
    for (int r = wid; r < n; r += nw) {
        int g = batch[r];
        ushort4 u = *reinterpret_cast<const ushort4*>(hb + (size_t)r * D + c);
        float* mp = mb + (size_t)g * (2 * D) + c;
        atomicAdd(mp + 0, b2f(u.x));
        atomicAdd(mp + 1, b2f(u.y));
        atomicAdd(mp + 2, b2f(u.z));
        atomicAdd(mp + 3, b2f(u.w));
        if (lane == 0) atomicAdd(&cg[g], 1.f);
    }
}

// xp scatter (dst-chunked): XPC[a1[r]-lo] += HB[a0[r]] for a1 in [lo,hi); CN2[a1]+=1
__global__ void k_xp_scatter(float* __restrict__ xpc, const u16* __restrict__ hb,
                             const int* __restrict__ a0, const int* __restrict__ a1,
                             float* __restrict__ cn2, int n, int lo, int hi) {
    int wid = (blockIdx.x * blockDim.x + threadIdx.x) >> 6;
    int lane = threadIdx.x & 63;
    int nw = (gridDim.x * blockDim.x) >> 6;
    int c = lane * 4;
    for (int r = wid; r < n; r += nw) {
        int g = a1[r];
        if (g < lo || g >= hi) continue;
        int s = a0[r];
        ushort4 u = *reinterpret_cast<const ushort4*>(hb + (size_t)s * D + c);
        float* xp = xpc + (size_t)(g - lo) * D + c;
        atomicAdd(xp + 0, b2f(u.x));
        atomicAdd(xp + 1, b2f(u.y));
        atomicAdd(xp + 2, b2f(u.z));
        atomicAdd(xp + 3, b2f(u.w));
        if (lane == 0) atomicAdd(&cn2[g], 1.f);
    }
}

// XPB rows [lo,lo+rows) = bf16(XPC / max(cnt,1))
__global__ void k_div_cvt(u16* __restrict__ xpb, const float* __restrict__ xpc,
                          const float* __restrict__ cn2, int lo, int rows) {
    size_t n = (size_t)rows * D;
    size_t i = (size_t)blockIdx.x * blockDim.x + threadIdx.x;
    size_t st = (size_t)gridDim.x * blockDim.x;
    for (; i < n; i += st) {
        int r = (int)(i >> 8);
        xpb[(size_t)(lo + r) * D + (i & (D - 1))] = f2b(xpc[i] / fmaxf(cn2[lo + r], 1.f));
    }
}

// conv scatter (dst-chunked): OC[d2[e]-lo] += HN[s2[e]] for d2 in [lo,hi)
__global__ void k_conv_scatter(float* __restrict__ oc, const u16* __restrict__ hn,
                               const int* __restrict__ s2, const int* __restrict__ d2,
                               int ne, int lo, int hi) {
    int wid = (blockIdx.x * blockDim.x + threadIdx.x) >> 6;
    int lane = threadIdx.x & 63;
    int nw = (gridDim.x * blockDim.x) >> 6;
    int c = lane * 4;
    for (int e = wid; e < ne; e += nw) {
        int d = d2[e];
        if (d < lo || d >= hi) continue;
        int s = s2[e];
        ushort4 u = *reinterpret_cast<const ushort4*>(hn + (size_t)s * D + c);
        float* op = oc + (size_t)(d - lo) * D + c;
        atomicAdd(op + 0, b2f(u.x));
        atomicAdd(op + 1, b2f(u.y));
        atomicAdd(op + 2, b2f(u.z));
        atomicAdd(op + 3, b2f(u.w));
    }
}

// X2B rows [lo,lo+rows) = bf16(relu(OC))
__global__ void k_relu_cvt(u16* __restrict__ x2b, const float* __restrict__ oc,
                           int lo, int rows) {
    size_t n = (size_t)rows * D;
    size_t i = (size_t)blockIdx.x * blockDim.x + threadIdx.x;
    size_t st = (size_t)gridDim.x * blockDim.x;
    for (; i < n; i += st)
        x2b[(size_t)lo * D + i] = f2b(fmaxf(oc[i], 0.f));
}

// x2 pool from f32 chunk with fused relu: Mb[batch2[lo+r], D:2D] += relu(OC[r]); CG2 += 1
__global__ void k_x2_pool(const float* __restrict__ oc, const int* __restrict__ batch2,
                          float* __restrict__ mb, float* __restrict__ cg2, int lo, int rows) {
    int wid = (blockIdx.x * blockDim.x + threadIdx.x) >> 6;
    int lane = threadIdx.x & 63;
    int nw = (gridDim.x * blockDim.x) >> 6;
    int c = lane * 4;
    for (int r = wid; r < rows; r += nw) {
        int g = batch2[lo + r];
        float4 v = *reinterpret_cast<const float4*>(oc + (size_t)r * D + c);
        float* mp = mb + (size_t)g * (2 * D) + D + c;
        atomicAdd(mp + 0, fmaxf(v.x, 0.f));
        atomicAdd(mp + 1, fmaxf(v.y, 0.f));
        atomicAdd(mp + 2, fmaxf(v.z, 0.f));
        atomicAdd(mp + 3, fmaxf(v.w, 0.f));
        if (lane == 0) atomicAdd(&cg2[g], 1.f);
    }
}

__global__ void k_seg_div(float* __restrict__ p, int ld, const float* __restrict__ cnt, int rows) {
    int r = blockIdx.x;
    if (r >= rows) return;
    p[(size_t)r * ld + threadIdx.x] /= fmaxf(cnt[r], 1.f);
}

// out rows [chunk-local] = (bias?bias:0) + iso[lo+r,:8] @ Wb   (Wb: [NI2, D])
template<int OBF>
__global__ void k_init_iso(void* __restrict__ outv, const float* __restrict__ iso,
                           const float* __restrict__ Wb, const float* __restrict__ bias,
                           int lo, int rows) {
    int wid = (blockIdx.x * blockDim.x + threadIdx.x) >> 6;
    int lane = threadIdx.x & 63;
    int nw = (gridDim.x * blockDim.x) >> 6;
    int c = lane * 4;
    for (int r = wid; r < rows; r += nw) {
        const float* ir = iso + (size_t)(lo + r) * NI2;
        float f[NI2];
        #pragma unroll
        for (int k = 0; k < NI2; ++k) f[k] = ir[k];
        #pragma unroll
        for (int j = 0; j < 4; ++j) {
            int cc = c + j;
            float v = bias ? bias[cc] : 0.f;
            #pragma unroll
            for (int k = 0; k < NI2; ++k) v += f[k] * Wb[k * D + cc];
            if (OBF) ((u16*)outv)[(size_t)r * D + cc] = f2b(v);
            else     ((float*)outv)[(size_t)r * D + cc] = v;
        }
    }
}

// [NG,64] @ [64,1] + b
__global__ void k_last(const float* __restrict__ f3, const float* __restrict__ w,
                       const float* __restrict__ b, float* __restrict__ out, int gn) {
    int g = blockIdx.x * 4 + (threadIdx.x >> 6);
    int lane = threadIdx.x & 63;
    if (g >= gn) return;
    float v = f3[(size_t)g * 64 + lane] * w[lane];
    #pragma unroll
    for (int off = 32; off; off >>= 1) v += __shfl_down(v, off);
    if (lane == 0) out[g] = v + b[0];
}

// ---------------- host ----------------
static inline dim3 ggrid(int M, int N) { return dim3((N + 63) / 64, (M + 63) / 64); }
static inline int imin(int a, int b) { return a < b ? a : b; }

extern "C" void kernel_launch(void* const* d_in, const int* in_sizes, int n_in,
                              void* d_out, int out_size, void* d_ws, size_t ws_size,
                              hipStream_t stream) {
    const float* x      = (const float*)d_in[0];
    const int*   eidx   = (const int*)  d_in[1];
    const int*   eattr  = (const int*)  d_in[2];
    const float* iso    = (const float*)d_in[3];
    const int*   eidx2  = (const int*)  d_in[4];
    const int*   assign = (const int*)  d_in[5];
    const int*   batch  = (const int*)  d_in[6];
    const int*   batch2 = (const int*)  d_in[7];
    const float* W_emb  = (const float*)d_in[8];
    const float* b_emb  = (const float*)d_in[9];
    const float* etab   = (const float*)d_in[10];
    const float* epsv   = (const float*)d_in[11];
    const float* gw1    = (const float*)d_in[12];
    const float* gb1    = (const float*)d_in[13];
    const float* gw2    = (const float*)d_in[14];
    const float* gb2    = (const float*)d_in[15];
    const float* bng    = (const float*)d_in[16];
    const float* bnb    = (const float*)d_in[17];
    const float* i1ws   = (const float*)d_in[18];
    const float* i1wn   = (const float*)d_in[19];
    const float* i1b    = (const float*)d_in[20];
    const float* i2ws   = (const float*)d_in[21];
    const float* i2wn   = (const float*)d_in[22];
    const float* i2b    = (const float*)d_in[23];
    const float* fc0w   = (const float*)d_in[24];
    const float* fc0b   = (const float*)d_in[25];
    const float* fc1w   = (const float*)d_in[26];
    const float* fc1b   = (const float*)d_in[27];
    const float* fc2w   = (const float*)d_in[28];
    const float* fc2b   = (const float*)d_in[29];
    const float* lw     = (const float*)d_in[30];
    const float* lb     = (const float*)d_in[31];

    float* out = (float*)d_out;
    char*  ws  = (char*)d_ws;

    if (ws_size < WS_BYTES) {
        k_fill<<<32, 256, 0, stream>>>(out, out_size, 10000.0f + (float)(ws_size >> 20));
        return;
    }

    float* Z   = (float*)(ws + Z_OFF);
    u16*   HB  = (u16*)  (ws + HB_OFF);
    float* TC  = (float*)(ws + TC_OFF);
    u16*   XPB = (u16*)  (ws + XPB_OFF);   // also X2B (in-place), also conv2 input
    float* XPC = (float*)(ws + XPC_OFF);
    u16*   HN  = (u16*)  (ws + HN_OFF);    // also HN2
    float* OC  = (float*)(ws + OC_OFF);
    float* F1  = (float*)(ws + F1_OFF);
    float* F2  = (float*)(ws + F2_OFF);
    float* F3  = (float*)(ws + F3_OFF);
    float* Mb  = (float*)(ws + MB_OFF);
    float* CG  = (float*)(ws + CG_OFF);
    float* CN2 = (float*)(ws + CN2_OFF);
    float* CG2 = (float*)(ws + CG2_OFF);
    float* BS  = (float*)(ws + BS_OFF);
    float* SC  = (float*)(ws + SC_OFF);
    float* SH  = (float*)(ws + SH_OFF);

    const size_t ND  = (size_t)NA * D;
    dim3 ew(8192);       // grid-stride elementwise
    dim3 sg(2048);       // wave-stride scatter (8192 waves)

    // zero Mb + CG + CN2 + CG2 (contiguous in tail)
    k_zero<<<dim3(2048), 256, 0, stream>>>(Mb, ((size_t)NG * 2 * D) + NG + NN2 + NG);

    // atom embedding: HB = relu(x @ W_emb + b_emb)
    k_gemm<0,1><<<ggrid(NA, D), 256, 0, stream>>>(x, FEAT, W_emb, D, b_emb, HB, D, NA, D, FEAT, 1, 0);

    // ---- GIN stack ----
    for (int l = 0; l < NL; ++l) {
        k_scale<<<ew, 256, 0, stream>>>(Z, HB, epsv, l, ND);
        k_edge_gin<<<sg, 256, 0, stream>>>(HB, etab + (size_t)l * 4 * D,
                                           eidx, eidx + NE, eattr, Z, NE);
        for (int c = 0; c < NA / CH; ++c) {
            k_gemm<0,0><<<ggrid(CH, 2 * D), 256, 0, stream>>>(
                Z + (size_t)c * CH * D, D, gw1 + (size_t)l * D * 2 * D, 2 * D,
                gb1 + (size_t)l * 2 * D, TC, 2 * D, CH, 2 * D, D, 1, 0);
            k_gemm<0,1><<<ggrid(CH, D), 256, 0, stream>>>(
                TC, 2 * D, gw2 + (size_t)l * 2 * D * D, D,
                gb2 + (size_t)l * D, HB + (size_t)c * CH * D, D, CH, D, 2 * D, 0, 0);
        }
        k_zero<<<dim3(1), 256, 0, stream>>>(BS, 2 * D);  // BS+BQ contiguous
        k_bn_stats<<<dim3(512), 256, 0, stream>>>(HB, BS, BS + D, NA);
        k_bn_final<<<dim3(1), 256, 0, stream>>>(BS, BS + D, bng + (size_t)l * D, bnb + (size_t)l * D, SC, SH, NA);
        k_bn_apply<<<ew, 256, 0, stream>>>(HB, SC, SH, ND, l < NL - 1 ? 1 : 0);
    }

    // ---- x_1 pooling ----
    k_pool1<<<sg, 256, 0, stream>>>(Mb, HB, batch, CG, NA);
    k_seg_div<<<dim3(NG), 256, 0, stream>>>(Mb, 2 * D, CG, NG);

    // ---- xp = segment_mean(HB[assign0], assign1), dst-chunked f32 accumulation ----
    for (int lo = 0; lo < NN2; lo += XCH) {
        int rows = imin(XCH, NN2 - lo);
        k_zero<<<ew, 256, 0, stream>>>(XPC, (size_t)rows * D);
        k_xp_scatter<<<sg, 256, 0, stream>>>(XPC, HB, assign, assign + NASS, CN2, NASS, lo, lo + rows);
        k_div_cvt<<<ew, 256, 0, stream>>>(XPB, XPC, CN2, lo, rows);
    }
    // HB dead from here

    // ---- GraphConv 1 ----
    // HN = [xp | iso] @ i1wn  (bf16)
    k_init_iso<1><<<sg, 256, 0, stream>>>(HN, iso, i1wn + (size_t)D * D, nullptr, 0, NN2);
    k_gemm<1,1><<<ggrid(NN2, D), 256, 0, stream>>>(XPB, D, i1wn, D, nullptr, HN, D, NN2, D, D, 0, 1);
    // OC chunks: self-path + scatter + relu -> X2B (in-place over XPB chunk)
    for (int lo = 0; lo < NN2; lo += OCH) {
        int rows = imin(OCH, NN2 - lo);
        k_init_iso<0><<<sg, 256, 0, stream>>>(OC, iso, i1ws + (size_t)D * D, i1b, lo, rows);
        k_gemm<1,0><<<ggrid(rows, D), 256, 0, stream>>>(XPB + (size_t)lo * D, D, i1ws, D, nullptr,
                                                        OC, D, rows, D, D, 0, 1);
        k_conv_scatter<<<sg, 256, 0, stream>>>(OC, HN, eidx2, eidx2 + NE2, NE2, lo, lo + rows);
        k_relu_cvt<<<ew, 256, 0, stream>>>(XPB, OC, lo, rows);
    }

    // ---- GraphConv 2 ----
    // HN2 = X2B @ i2wn (bf16, reuses HN region)
    k_gemm<1,1><<<ggrid(NN2, D), 256, 0, stream>>>(XPB, D, i2wn, D, nullptr, HN, D, NN2, D, D, 0, 0);
    for (int lo = 0; lo < NN2; lo += OCH) {
        int rows = imin(OCH, NN2 - lo);
        k_gemm<1,0><<<ggrid(rows, D), 256, 0, stream>>>(XPB + (size_t)lo * D, D, i2ws, D, i2b,
                                                        OC, D, rows, D, D, 0, 0);
        k_conv_scatter<<<sg, 256, 0, stream>>>(OC, HN, eidx2, eidx2 + NE2, NE2, lo, lo + rows);
        k_x2_pool<<<sg, 256, 0, stream>>>(OC, batch2, Mb, CG2, lo, rows);
    }
    k_seg_div<<<dim3(NG), 256, 0, stream>>>(Mb + D, 2 * D, CG2, NG);

    // ---- FC head ----
    k_gemm<0,0><<<ggrid(NG, D), 256, 0, stream>>>(Mb, 2 * D, fc0w, D, fc0b, F1, D, NG, D, 2 * D, 1, 0);
    k_gemm<0,0><<<ggrid(NG, D / 2), 256, 0, stream>>>(F1, D, fc1w, D / 2, fc1b, F2, D / 2, NG, D / 2, D, 1, 0);
    k_gemm<0,0><<<ggrid(NG, D / 4), 256, 0, stream>>>(F2, D / 2, fc2w, D / 4, fc2b, F3, D / 4, NG, D / 4, D / 2, 1, 0);
    k_last<<<dim3((NG + 3) / 4), 256, 0, stream>>>(F3, lw, lb, out, NG);
}

// Round 5
// 3908.504 us; speedup vs baseline: 3.9186x; 3.9186x over previous
//
#include <hip/hip_runtime.h>
#include <cstddef>

// ---------------- problem constants ----------------
constexpr int NA   = 100000;
constexpr int NE   = 200000;
constexpr int NN2  = 200000;
constexpr int NASS = 400000;
constexpr int NE2  = 400000;
constexpr int NG   = 5000;
constexpr int D    = 256;
constexpr int FEAT = 40;
constexpr int NI2  = 8;
constexpr int NL   = 5;
constexpr int CH   = 25000;   // GIN hidden chunk rows (NA = 4*CH)

typedef unsigned short u16;
typedef __attribute__((ext_vector_type(8))) short bf16x8;
typedef __attribute__((ext_vector_type(4))) float f32x4;

static __device__ __forceinline__ float b2f(u16 s) {
    union { unsigned int u; float f; } v; v.u = ((unsigned int)s) << 16; return v.f;
}
static __device__ __forceinline__ u16 f2b(float f) {
    union { unsigned int u; float f; } v; v.f = f;
    unsigned int r = v.u + 0x7FFFu + ((v.u >> 16) & 1u);
    return (u16)(r >> 16);
}

// ---------------- workspace layout (byte offsets); ws_size = 240 MiB = 251,658,240 ----------------
// GIN:  HB f32[NA,256]@0 (102.4M) | ZB bf16[NA,256]@102.4M (51.2M) | TC f32[CH,512]@153.6M (51.2M)
// emb:  XEMB f32[NA,64]@102.4M (25.6M, pre-GIN only)
// conv: XPB bf16[NN2,256]@102.4M (over ZB+TC; HB still live for gather) ; HN bf16[NN2,256]@0 (HB dead)
constexpr size_t HB_OFF   = 0;
constexpr size_t ZB_OFF   = 102400000;
constexpr size_t TC_OFF   = 153600000;
constexpr size_t XEMB_OFF = 102400000;
constexpr size_t XPB_OFF  = 102400000;
constexpr size_t HN_OFF   = 0;
// tail
constexpr size_t MB_OFF   = 204800000;   // f32 [NG,512]
constexpr size_t F1_OFF   = 215040000;   // f32 [NG,256] (also CSR pack scratch)
constexpr size_t F2_OFF   = 220160000;
constexpr size_t F3_OFF   = 222720000;
constexpr size_t WEMT_OFF = 224000000;   // bf16 2 planes [256][64]
constexpr size_t GW1T_OFF = 224065536;   // bf16 5 x 2 planes [512][256]
constexpr size_t GW2T_OFF = 226686976;   // bf16 5 x 2 planes [256][512]
constexpr size_t IWT_OFF  = 229308416;   // bf16 4 weights x 2 planes [256][256]
constexpr size_t EOFF_OFF = 230400000;   // int [NA+1]
constexpr size_t EIDS_OFF = 230800768;   // int [NE] packed src<<2|attr
constexpr size_t AOFF_OFF = 231600832;   // int [NN2+1]
constexpr size_t AIDS_OFF = 232400896;   // int [NASS]
constexpr size_t E2OFF_OFF= 234000960;   // int [NN2+1]
constexpr size_t E2IDS_OFF= 234801024;   // int [NE2]
constexpr size_t CUR_OFF  = 236401088;   // int [NN2]
constexpr size_t PART_OFF = 237201152;   // int [256]
constexpr size_t GST_OFF  = 237202240;   // int [NG+1]
constexpr size_t G2ST_OFF = 237222272;   // int [NG+1]
constexpr size_t BS_OFF   = 237242304;   // f32 [512]
constexpr size_t SC_OFF   = 237244416;   // f32 [256]
constexpr size_t SH_OFF   = 237245440;   // f32 [256]
constexpr size_t WS_BYTES = 237246464;

// ---------------- MFMA bf16 GEMM with split (hi+lo) weights ----------------
// C[M,N] = A[M,K] @ (Bhi+Blo)[N,K]^T [+bias] [+iso@wtail] [relu]
// AF32: A is f32, split on the fly (adds Al·Bh chain). CF32: C stored f32, else bf16.
// BM=128, BN=256 (grid.x = N/256 exact), BK=32, 512 threads = 8 waves (2x4 of 64x64 tiles).
template<int BIAS, int RELU, int ISO, int AF32, int CF32>
__global__ __launch_bounds__(512) void k_mgemm(
    const void* __restrict__ Av, int lda,
    const u16* __restrict__ Bt,      // hi plane [N][K]; lo plane at +N*K
    const float* __restrict__ bias,
    const float* __restrict__ iso,   // [M][8] f32 (ISO)
    const float* __restrict__ wtail, // [8][256] f32 (ISO; requires N==256)
    void* __restrict__ Cv, int ldc,
    int M, int N, int K)
{
    __shared__ __align__(16) u16 Ah[128][40];
    __shared__ __align__(16) u16 Al[AF32 ? 128 : 1][40];
    __shared__ __align__(16) u16 Bh[256][40];
    __shared__ __align__(16) u16 Bl[256][40];
    const int tid = threadIdx.x;
    const int wave = tid >> 6, lane = tid & 63;
    const int wr = wave >> 2, wc = wave & 3;
    const int bm = blockIdx.y * 128, bn = blockIdx.x * 256;
    const int l15 = lane & 15, lhi = lane >> 4;
    const int ar = tid >> 2, ac = (tid & 3) << 3;
    const u16* Blo = Bt + (size_t)N * K;
    f32x4 acc[4][4] = {};
    const int ktiles = K >> 5;
    for (int kt = 0; kt < ktiles; ++kt) {
        const int k0 = kt << 5;
        ushort4 a0h = {0,0,0,0}, a1h = {0,0,0,0}, a0l = {0,0,0,0}, a1l = {0,0,0,0};
        if (AF32) {
            float4 v0 = {0,0,0,0}, v1 = {0,0,0,0};
            if (bm + ar < M) {
                const float* ap = (const float*)Av + (size_t)(bm + ar) * lda + k0 + ac;
                v0 = *(const float4*)ap; v1 = *(const float4*)(ap + 4);
            }
            a0h.x = f2b(v0.x); a0h.y = f2b(v0.y); a0h.z = f2b(v0.z); a0h.w = f2b(v0.w);
            a1h.x = f2b(v1.x); a1h.y = f2b(v1.y); a1h.z = f2b(v1.z); a1h.w = f2b(v1.w);
            a0l.x = f2b(v0.x - b2f(a0h.x)); a0l.y = f2b(v0.y - b2f(a0h.y));
            a0l.z = f2b(v0.z - b2f(a0h.z)); a0l.w = f2b(v0.w - b2f(a0h.w));
            a1l.x = f2b(v1.x - b2f(a1h.x)); a1l.y = f2b(v1.y - b2f(a1h.y));
            a1l.z = f2b(v1.z - b2f(a1h.z)); a1l.w = f2b(v1.w - b2f(a1h.w));
        } else {
            if (bm + ar < M) {
                const u16* ap = (const u16*)Av + (size_t)(bm + ar) * lda + k0 + ac;
                a0h = *(const ushort4*)ap; a1h = *(const ushort4*)(ap + 4);
            }
        }
        const u16* bp0h = Bt  + (size_t)(bn + ar) * K + k0 + ac;
        const u16* bp1h = Bt  + (size_t)(bn + 128 + ar) * K + k0 + ac;
        const u16* bp0l = Blo + (size_t)(bn + ar) * K + k0 + ac;
        const u16* bp1l = Blo + (size_t)(bn + 128 + ar) * K + k0 + ac;
        ushort4 b00h = *(const ushort4*)bp0h, b01h = *(const ushort4*)(bp0h + 4);
        ushort4 b10h = *(const ushort4*)bp1h, b11h = *(const ushort4*)(bp1h + 4);
        ushort4 b00l = *(const ushort4*)bp0l, b01l = *(const ushort4*)(bp0l + 4);
        ushort4 b10l = *(const ushort4*)bp1l, b11l = *(const ushort4*)(bp1l + 4);
        __syncthreads();
        *(ushort4*)&Ah[ar][ac] = a0h; *(ushort4*)&Ah[ar][ac + 4] = a1h;
        if (AF32) { *(ushort4*)&Al[ar][ac] = a0l; *(ushort4*)&Al[ar][ac + 4] = a1l; }
        *(ushort4*)&Bh[ar][ac] = b00h;       *(ushort4*)&Bh[ar][ac + 4] = b01h;
        *(ushort4*)&Bh[128 + ar][ac] = b10h; *(ushort4*)&Bh[128 + ar][ac + 4] = b11h;
        *(ushort4*)&Bl[ar][ac] = b00l;       *(ushort4*)&Bl[ar][ac + 4] = b01l;
        *(ushort4*)&Bl[128 + ar][ac] = b10l; *(ushort4*)&Bl[128 + ar][ac + 4] = b11l;
        __syncthreads();
        bf16x8 fah[4], fal[4], fbh[4], fbl[4];
        #pragma unroll
        for (int m = 0; m < 4; ++m) {
            fah[m] = *(const bf16x8*)&Ah[wr * 64 + m * 16 + l15][lhi * 8];
            if (AF32) fal[m] = *(const bf16x8*)&Al[wr * 64 + m * 16 + l15][lhi * 8];
        }
        #pragma unroll
        for (int n = 0; n < 4; ++n) {
            fbh[n] = *(const bf16x8*)&Bh[wc * 64 + n * 16 + l15][lhi * 8];
            fbl[n] = *(const bf16x8*)&Bl[wc * 64 + n * 16 + l15][lhi * 8];
        }
        #pragma unroll
        for (int m = 0; m < 4; ++m)
            #pragma unroll
            for (int n = 0; n < 4; ++n) {
                acc[m][n] = __builtin_amdgcn_mfma_f32_16x16x32_bf16(fah[m], fbh[n], acc[m][n], 0, 0, 0);
                acc[m][n] = __builtin_amdgcn_mfma_f32_16x16x32_bf16(fah[m], fbl[n], acc[m][n], 0, 0, 0);
                if (AF32)
                    acc[m][n] = __builtin_amdgcn_mfma_f32_16x16x32_bf16(fal[m], fbh[n], acc[m][n], 0, 0, 0);
            }
    }
    // epilogue: C/D layout col=lane&15, row=(lane>>4)*4+reg [m89-verified]
    #pragma unroll
    for (int m = 0; m < 4; ++m) {
        int rbase = bm + wr * 64 + m * 16 + lhi * 4;
        #pragma unroll
        for (int n = 0; n < 4; ++n) {
            int col = bn + wc * 64 + n * 16 + l15;
            #pragma unroll
            for (int r = 0; r < 4; ++r) {
                int row = rbase + r;
                if (row >= M) continue;
                float v = acc[m][n][r];
                if (BIAS) v += bias[col];
                if (ISO) {
                    const float* ir = iso + (size_t)row * NI2;
                    #pragma unroll
                    for (int k = 0; k < NI2; ++k) v += ir[k] * wtail[k * 256 + col];
                }
                if (RELU) v = fmaxf(v, 0.f);
                size_t cidx = (size_t)row * ldc + col;
                if (CF32) ((float*)Cv)[cidx] = v;
                else      ((u16*)Cv)[cidx] = f2b(v);
            }
        }
    }
}

// ---------------- fp32 tiled GEMM (FC head only) ----------------
__global__ __launch_bounds__(256) void k_gemm(
    const float* __restrict__ A, int lda,
    const float* __restrict__ B, int ldb,
    const float* __restrict__ bias,
    float* __restrict__ C, int ldc,
    int M, int N, int K, int relu)
{
    __shared__ __align__(16) float As[16][68];
    __shared__ __align__(16) float Bs[16][68];
    const int tid = threadIdx.x;
    const int tx = tid & 15, ty = tid >> 4;
    const int bm = blockIdx.y * 64, bn = blockIdx.x * 64;
    const int arow = tid >> 2, akq = (tid & 3) << 2;
    const int bk = tid >> 4, bnq = (tid & 15) << 2;
    float c[4][4] = {};
    const int ktiles = (K + 15) >> 4;
    for (int kt = 0; kt < ktiles; ++kt) {
        const int k0 = kt << 4;
        float4 av = make_float4(0.f, 0.f, 0.f, 0.f);
        if (bm + arow < M && k0 + akq + 4 <= K)
            av = *reinterpret_cast<const float4*>(A + (size_t)(bm + arow) * lda + (k0 + akq));
        As[akq + 0][arow] = av.x; As[akq + 1][arow] = av.y;
        As[akq + 2][arow] = av.z; As[akq + 3][arow] = av.w;
        float4 bv = make_float4(0.f, 0.f, 0.f, 0.f);
        if (k0 + bk < K && bn + bnq + 4 <= N)
            bv = *reinterpret_cast<const float4*>(B + (size_t)(k0 + bk) * ldb + (bn + bnq));
        *reinterpret_cast<float4*>(&Bs[bk][bnq]) = bv;
        __syncthreads();
        #pragma unroll
        for (int k = 0; k < 16; ++k) {
            float a0 = As[k][ty*4+0], a1 = As[k][ty*4+1], a2 = As[k][ty*4+2], a3 = As[k][ty*4+3];
            float b0 = Bs[k][tx*4+0], b1 = Bs[k][tx*4+1], b2 = Bs[k][tx*4+2], b3 = Bs[k][tx*4+3];
            c[0][0]+=a0*b0;c[0][1]+=a0*b1;c[0][2]+=a0*b2;c[0][3]+=a0*b3;
            c[1][0]+=a1*b0;c[1][1]+=a1*b1;c[1][2]+=a1*b2;c[1][3]+=a1*b3;
            c[2][0]+=a2*b0;c[2][1]+=a2*b1;c[2][2]+=a2*b2;c[2][3]+=a2*b3;
            c[3][0]+=a3*b0;c[3][1]+=a3*b1;c[3][2]+=a3*b2;c[3][3]+=a3*b3;
        }
        __syncthreads();
    }
    #pragma unroll
    for (int i = 0; i < 4; ++i) {
        int row = bm + ty * 4 + i;
        if (row >= M) continue;
        #pragma unroll
        for (int j = 0; j < 4; ++j) {
            int col = bn + tx * 4 + j;
            if (col >= N) continue;
            float v = c[i][j] + bias[col];
            if (relu) v = fmaxf(v, 0.f);
            C[(size_t)row * ldc + col] = v;
        }
    }
}

// ---------------- utility ----------------
__global__ void k_zero(float* __restrict__ p, size_t n) {
    size_t i = (size_t)blockIdx.x * blockDim.x + threadIdx.x;
    size_t st = (size_t)gridDim.x * blockDim.x;
    for (; i < n; i += st) p[i] = 0.f;
}
__global__ void k_fill(float* __restrict__ p, int n, float v) {
    int i = blockIdx.x * blockDim.x + threadIdx.x;
    int st = gridDim.x * blockDim.x;
    for (; i < n; i += st) p[i] = v;
}

// ---------------- CSR build ----------------
__global__ void k_count(const int* __restrict__ idx, int n, int* __restrict__ cnt) {
    int i = blockIdx.x * blockDim.x + threadIdx.x;
    int st = gridDim.x * blockDim.x;
    for (; i < n; i += st) atomicAdd(&cnt[idx[i]], 1);
}
__global__ void k_scan_partial(const int* __restrict__ cnt, int n, int* __restrict__ part) {
    __shared__ int sm[256];
    int c = blockIdx.x, t = threadIdx.x;
    int base = c * 4096 + t * 16;
    int s = 0;
    #pragma unroll
    for (int j = 0; j < 16; ++j) { int i = base + j; if (i < n) s += cnt[i]; }
    sm[t] = s; __syncthreads();
    for (int o = 128; o; o >>= 1) { if (t < o) sm[t] += sm[t + o]; __syncthreads(); }
    if (t == 0) part[c] = sm[0];
}
__global__ void k_scan_mid(int* __restrict__ part, int nch, int* __restrict__ off, int n) {
    if (threadIdx.x == 0 && blockIdx.x == 0) {
        int run = 0;
        for (int c = 0; c < nch; ++c) { int v = part[c]; part[c] = run; run += v; }
        off[n] = run;
    }
}
__global__ void k_scan_final(const int* __restrict__ cnt, int n, const int* __restrict__ part,
                             int* __restrict__ off) {
    __shared__ int sm[256];
    int c = blockIdx.x, t = threadIdx.x;
    int base = c * 4096 + t * 16;
    int loc[16]; int s = 0;
    #pragma unroll
    for (int j = 0; j < 16; ++j) { int i = base + j; int v = (i < n) ? cnt[i] : 0; loc[j] = s; s += v; }
    sm[t] = s; __syncthreads();
    for (int o = 1; o < 256; o <<= 1) {
        int v = (t >= o) ? sm[t - o] : 0;
        __syncthreads(); sm[t] += v; __syncthreads();
    }
    int tpre = (t == 0) ? 0 : sm[t - 1];
    int cb = part[c];
    #pragma unroll
    for (int j = 0; j < 16; ++j) { int i = base + j; if (i < n) off[i] = cb + tpre + loc[j]; }
}
__global__ void k_fill_csr(const int* __restrict__ idx, const int* __restrict__ pay, int n,
                           const int* __restrict__ off, int* __restrict__ cur, int* __restrict__ ids) {
    int i = blockIdx.x * blockDim.x + threadIdx.x;
    int st = gridDim.x * blockDim.x;
    for (; i < n; i += st) {
        int d = idx[i];
        int p = off[d] + atomicAdd(&cur[d], 1);
        ids[p] = pay[i];
    }
}
__global__ void k_pack(const int* __restrict__ src, const int* __restrict__ attr,
                       int* __restrict__ pk, int n) {
    int i = blockIdx.x * blockDim.x + threadIdx.x;
    int st = gridDim.x * blockDim.x;
    for (; i < n; i += st) pk[i] = (src[i] << 2) | attr[i];
}
__global__ void k_lbound(const int* __restrict__ arr, int n, int nseg, int* __restrict__ st) {
    int g = blockIdx.x * blockDim.x + threadIdx.x;
    if (g > nseg) return;
    int lo = 0, hi = n;
    while (lo < hi) { int mid = (lo + hi) >> 1; if (arr[mid] < g) lo = mid + 1; else hi = mid; }
    st[g] = lo;
}

// ---------------- weight prep (hi/lo split planes, transposed [N][K]) ----------------
__global__ void k_wt(const float* __restrict__ w, u16* __restrict__ wt, int K, int N) {
    int i = blockIdx.x * blockDim.x + threadIdx.x;
    int tot = K * N, st = gridDim.x * blockDim.x;
    for (; i < tot; i += st) {
        int n_ = i / K, k = i - n_ * K;
        float v = w[(size_t)k * N + n_];
        u16 h = f2b(v);
        wt[i] = h;
        wt[(size_t)tot + i] = f2b(v - b2f(h));
    }
}
__global__ void k_wembT(const float* __restrict__ w, u16* __restrict__ wt) {
    int i = blockIdx.x * blockDim.x + threadIdx.x;
    if (i >= 256 * 64) return;
    int n_ = i >> 6, k = i & 63;
    float v = (k < FEAT) ? w[(size_t)k * 256 + n_] : 0.f;
    u16 h = f2b(v);
    wt[i] = h;
    wt[256 * 64 + i] = f2b(v - b2f(h));
}
__global__ void k_xemb(const float* __restrict__ x, float* __restrict__ xe) {
    size_t i = (size_t)blockIdx.x * blockDim.x + threadIdx.x;
    size_t st = (size_t)gridDim.x * blockDim.x;
    size_t tot = (size_t)NA * 64;
    for (; i < tot; i += st) {
        int r = (int)(i >> 6), c = (int)(i & 63);
        xe[i] = (c < FEAT) ? x[(size_t)r * FEAT + c] : 0.f;
    }
}

// ---------------- CSR gathers ----------------
// ZB[v] = bf16((1+eps)*HB[v] + sum_{e->v}(HB[src] + etab[attr]))   (HB f32)
__global__ void k_gin_gather(const float* __restrict__ hb, const int* __restrict__ off,
                             const int* __restrict__ ids, const float* __restrict__ etab_l,
                             const float* __restrict__ epsv, int l, u16* __restrict__ zb) {
    int wid = (blockIdx.x * blockDim.x + threadIdx.x) >> 6;
    int lane = threadIdx.x & 63;
    int nw = (gridDim.x * blockDim.x) >> 6;
    int c = lane * 4;
    float e1 = 1.f + epsv[l];
    for (int v = wid; v < NA; v += nw) {
        float4 h = *(const float4*)(hb + (size_t)v * D + c);
        float s0 = e1 * h.x, s1 = e1 * h.y, s2 = e1 * h.z, s3 = e1 * h.w;
        int p1 = off[v + 1];
        for (int p = off[v]; p < p1; ++p) {
            int pk = ids[p]; int src = pk >> 2; int at = pk & 3;
            float4 u = *(const float4*)(hb + (size_t)src * D + c);
            float4 t = *(const float4*)(etab_l + at * D + c);
            s0 += u.x + t.x; s1 += u.y + t.y; s2 += u.z + t.z; s3 += u.w + t.w;
        }
        ushort4 o; o.x = f2b(s0); o.y = f2b(s1); o.z = f2b(s2); o.w = f2b(s3);
        *(ushort4*)(zb + (size_t)v * D + c) = o;
    }
}
__global__ void k_xp_gather(const float* __restrict__ hb, const int* __restrict__ off,
                            const int* __restrict__ ids, u16* __restrict__ xpb) {
    int wid = (blockIdx.x * blockDim.x + threadIdx.x) >> 6;
    int lane = threadIdx.x & 63;
    int nw = (gridDim.x * blockDim.x) >> 6;
    int c = lane * 4;
    for (int v = wid; v < NN2; v += nw) {
        int p0 = off[v], p1 = off[v + 1];
        float s0 = 0, s1 = 0, s2 = 0, s3 = 0;
        for (int p = p0; p < p1; ++p) {
            const float* u = hb + (size_t)ids[p] * D + c;
            float4 uv = *(const float4*)u;
            s0 += uv.x; s1 += uv.y; s2 += uv.z; s3 += uv.w;
        }
        float inv = 1.f / fmaxf((float)(p1 - p0), 1.f);
        ushort4 o; o.x = f2b(s0 * inv); o.y = f2b(s1 * inv); o.z = f2b(s2 * inv); o.w = f2b(s3 * inv);
        *(ushort4*)(xpb + (size_t)v * D + c) = o;
    }
}
// val = SELF[v] + sum HN[nbr]; relu. POOL=0: overwrite SELF (bf16). POOL=1: atomicAdd into Mb[:,D:2D].
template<int POOL>
__global__ void k_conv_gather(u16* __restrict__ selfb, const u16* __restrict__ hn,
                              const int* __restrict__ off, const int* __restrict__ ids,
                              const int* __restrict__ batch2, float* __restrict__ mb) {
    int wid = (blockIdx.x * blockDim.x + threadIdx.x) >> 6;
    int lane = threadIdx.x & 63;
    int nw = (gridDim.x * blockDim.x) >> 6;
    int c = lane * 4;
    for (int v = wid; v < NN2; v += nw) {
        ushort4 sv = *(const ushort4*)(selfb + (size_t)v * D + c);
        float s0 = b2f(sv.x), s1 = b2f(sv.y), s2 = b2f(sv.z), s3 = b2f(sv.w);
        int p1 = off[v + 1];
        for (int p = off[v]; p < p1; ++p) {
            ushort4 u = *(const ushort4*)(hn + (size_t)ids[p] * D + c);
            s0 += b2f(u.x); s1 += b2f(u.y); s2 += b2f(u.z); s3 += b2f(u.w);
        }
        s0 = fmaxf(s0, 0.f); s1 = fmaxf(s1, 0.f); s2 = fmaxf(s2, 0.f); s3 = fmaxf(s3, 0.f);
        if (POOL) {
            float* mp = mb + (size_t)batch2[v] * (2 * D) + D + c;
            atomicAdd(mp + 0, s0); atomicAdd(mp + 1, s1);
            atomicAdd(mp + 2, s2); atomicAdd(mp + 3, s3);
        } else {
            ushort4 o; o.x = f2b(s0); o.y = f2b(s1); o.z = f2b(s2); o.w = f2b(s3);
            *(ushort4*)(selfb + (size_t)v * D + c) = o;
        }
    }
}

// ---------------- BN (f32 HB) ----------------
__global__ void k_bn_stats(const float* __restrict__ z, float* __restrict__ sum,
                           float* __restrict__ sumsq, int n) {
    int c = threadIdx.x;
    float s = 0.f, q = 0.f;
    for (int r = blockIdx.x; r < n; r += gridDim.x) {
        float v = z[(size_t)r * D + c];
        s += v; q += v * v;
    }
    atomicAdd(&sum[c], s);
    atomicAdd(&sumsq[c], q);
}
__global__ void k_bn_final(const float* __restrict__ sum, const float* __restrict__ sumsq,
                           const float* __restrict__ gamma, const float* __restrict__ beta,
                           float* __restrict__ scale, float* __restrict__ shift, int n) {
    int c = threadIdx.x;
    float mu = sum[c] / (float)n;
    float var = sumsq[c] / (float)n - mu * mu;
    float sc = gamma[c] * rsqrtf(var + 1e-5f);
    scale[c] = sc;
    shift[c] = beta[c] - mu * sc;
}
__global__ void k_bn_apply(float* __restrict__ h, const float* __restrict__ scale,
                           const float* __restrict__ shift, size_t n, int relu) {
    size_t i = (size_t)blockIdx.x * blockDim.x + threadIdx.x;
    size_t st = (size_t)gridDim.x * blockDim.x;
    for (; i < n; i += st) {
        int c = (int)(i & (D - 1));
        float v = scale[c] * h[i] + shift[c];
        if (relu) v = fmaxf(v, 0.f);
        h[i] = v;
    }
}

// ---------------- pooling / head ----------------
__global__ void k_pool1(const float* __restrict__ hb, const int* __restrict__ gst,
                        float* __restrict__ mb) {
    int g = blockIdx.x, t = threadIdx.x;
    int a = gst[g], b = gst[g + 1];
    float s = 0.f;
    for (int r = a; r < b; ++r) s += hb[(size_t)r * D + t];
    mb[(size_t)g * (2 * D) + t] = s / fmaxf((float)(b - a), 1.f);
}
__global__ void k_div2(float* __restrict__ mb, const int* __restrict__ g2st) {
    int g = blockIdx.x, t = threadIdx.x;
    float c = fmaxf((float)(g2st[g + 1] - g2st[g]), 1.f);
    mb[(size_t)g * (2 * D) + D + t] /= c;
}
__global__ void k_last(const float* __restrict__ f3, const float* __restrict__ w,
                       const float* __restrict__ b, float* __restrict__ out, int gn) {
    int g = blockIdx.x * 4 + (threadIdx.x >> 6);
    int lane = threadIdx.x & 63;
    if (g >= gn) return;
    float v = f3[(size_t)g * 64 + lane] * w[lane];
    #pragma unroll
    for (int off = 32; off; off >>= 1) v += __shfl_down(v, off);
    if (lane == 0) out[g] = v + b[0];
}

// ---------------- host ----------------
static inline dim3 ggrid(int M, int N) { return dim3((N + 63) / 64, (M + 63) / 64); }

extern "C" void kernel_launch(void* const* d_in, const int* in_sizes, int n_in,
                              void* d_out, int out_size, void* d_ws, size_t ws_size,
                              hipStream_t stream) {
    const float* x      = (const float*)d_in[0];
    const int*   eidx   = (const int*)  d_in[1];
    const int*   eattr  = (const int*)  d_in[2];
    const float* iso    = (const float*)d_in[3];
    const int*   eidx2  = (const int*)  d_in[4];
    const int*   assign = (const int*)  d_in[5];
    const int*   batch  = (const int*)  d_in[6];
    const int*   batch2 = (const int*)  d_in[7];
    const float* W_emb  = (const float*)d_in[8];
    const float* b_emb  = (const float*)d_in[9];
    const float* etab   = (const float*)d_in[10];
    const float* epsv   = (const float*)d_in[11];
    const float* gw1    = (const float*)d_in[12];
    const float* gb1    = (const float*)d_in[13];
    const float* gw2    = (const float*)d_in[14];
    const float* gb2    = (const float*)d_in[15];
    const float* bng    = (const float*)d_in[16];
    const float* bnb    = (const float*)d_in[17];
    const float* i1ws   = (const float*)d_in[18];
    const float* i1wn   = (const float*)d_in[19];
    const float* i1b    = (const float*)d_in[20];
    const float* i2ws   = (const float*)d_in[21];
    const float* i2wn   = (const float*)d_in[22];
    const float* i2b    = (const float*)d_in[23];
    const float* fc0w   = (const float*)d_in[24];
    const float* fc0b   = (const float*)d_in[25];
    const float* fc1w   = (const float*)d_in[26];
    const float* fc1b   = (const float*)d_in[27];
    const float* fc2w   = (const float*)d_in[28];
    const float* fc2b   = (const float*)d_in[29];
    const float* lw     = (const float*)d_in[30];
    const float* lb     = (const float*)d_in[31];

    float* out = (float*)d_out;
    char*  ws  = (char*)d_ws;
    if (ws_size < WS_BYTES) {
        k_fill<<<32, 256, 0, stream>>>(out, out_size, 10000.0f + (float)(ws_size >> 20));
        return;
    }

    float* HB   = (float*)(ws + HB_OFF);
    u16*   ZB   = (u16*)(ws + ZB_OFF);
    float* TC   = (float*)(ws + TC_OFF);
    float* XEMB = (float*)(ws + XEMB_OFF);
    u16*   XPB  = (u16*)(ws + XPB_OFF);   // xp -> conv1 self/out -> conv2 input/self (in place)
    u16*   HN   = (u16*)(ws + HN_OFF);    // conv neighbor transforms (over dead HB)
    float* Mb   = (float*)(ws + MB_OFF);
    float* F1   = (float*)(ws + F1_OFF);
    float* F2   = (float*)(ws + F2_OFF);
    float* F3   = (float*)(ws + F3_OFF);
    u16*   wembT= (u16*)(ws + WEMT_OFF);
    u16*   gw1T = (u16*)(ws + GW1T_OFF);
    u16*   gw2T = (u16*)(ws + GW2T_OFF);
    u16*   iwT  = (u16*)(ws + IWT_OFF);
    u16*   i1wnT= iwT;
    u16*   i1wsT= iwT + 2 * 65536;
    u16*   i2wnT= iwT + 4 * 65536;
    u16*   i2wsT= iwT + 6 * 65536;
    int*   eoff = (int*)(ws + EOFF_OFF);
    int*   eids = (int*)(ws + EIDS_OFF);
    int*   aoff = (int*)(ws + AOFF_OFF);
    int*   aids = (int*)(ws + AIDS_OFF);
    int*   e2off= (int*)(ws + E2OFF_OFF);
    int*   e2ids= (int*)(ws + E2IDS_OFF);
    int*   cur  = (int*)(ws + CUR_OFF);
    int*   part = (int*)(ws + PART_OFF);
    int*   gst  = (int*)(ws + GST_OFF);
    int*   g2st = (int*)(ws + G2ST_OFF);
    float* BS   = (float*)(ws + BS_OFF);
    float* SC   = (float*)(ws + SC_OFF);
    float* SH   = (float*)(ws + SH_OFF);
    int*   packs= (int*)F1;   // scratch: F1 unused until head

    const int* e_src = eidx;   const int* e_dst = eidx + NE;
    const int* a0    = assign; const int* a1    = assign + NASS;
    const int* s2    = eidx2;  const int* d2    = eidx2 + NE2;

    dim3 sg(2048);   // wave-stride gathers
    dim3 ew(8192);   // grid-stride elementwise
    const int nchA = (NA + 4095) / 4096;     // 25
    const int nch2 = (NN2 + 4095) / 4096;    // 49

    k_zero<<<dim3(1024), 256, 0, stream>>>(Mb, (size_t)NG * 2 * D);

    // pooling bounds (batch, batch_2 sorted)
    k_lbound<<<dim3((NG + 256) / 256), 256, 0, stream>>>(batch, NA, NG, gst);
    k_lbound<<<dim3((NG + 256) / 256), 256, 0, stream>>>(batch2, NN2, NG, g2st);

    // CSR: edges -> atoms
    k_zero<<<dim3(256), 256, 0, stream>>>((float*)cur, NA);
    k_count<<<dim3(1024), 256, 0, stream>>>(e_dst, NE, cur);
    k_scan_partial<<<dim3(nchA), 256, 0, stream>>>(cur, NA, part);
    k_scan_mid<<<dim3(1), 64, 0, stream>>>(part, nchA, eoff, NA);
    k_scan_final<<<dim3(nchA), 256, 0, stream>>>(cur, NA, part, eoff);
    k_zero<<<dim3(256), 256, 0, stream>>>((float*)cur, NA);
    k_pack<<<dim3(1024), 256, 0, stream>>>(e_src, eattr, packs, NE);
    k_fill_csr<<<dim3(1024), 256, 0, stream>>>(e_dst, packs, NE, eoff, cur, eids);

    // CSR: assignments -> 2-sets
    k_zero<<<dim3(256), 256, 0, stream>>>((float*)cur, NN2);
    k_count<<<dim3(1024), 256, 0, stream>>>(a1, NASS, cur);
    k_scan_partial<<<dim3(nch2), 256, 0, stream>>>(cur, NN2, part);
    k_scan_mid<<<dim3(1), 64, 0, stream>>>(part, nch2, aoff, NN2);
    k_scan_final<<<dim3(nch2), 256, 0, stream>>>(cur, NN2, part, aoff);
    k_zero<<<dim3(256), 256, 0, stream>>>((float*)cur, NN2);
    k_fill_csr<<<dim3(1024), 256, 0, stream>>>(a1, a0, NASS, aoff, cur, aids);

    // CSR: 2-set edges
    k_zero<<<dim3(256), 256, 0, stream>>>((float*)cur, NN2);
    k_count<<<dim3(1024), 256, 0, stream>>>(d2, NE2, cur);
    k_scan_partial<<<dim3(nch2), 256, 0, stream>>>(cur, NN2, part);
    k_scan_mid<<<dim3(1), 64, 0, stream>>>(part, nch2, e2off, NN2);
    k_scan_final<<<dim3(nch2), 256, 0, stream>>>(cur, NN2, part, e2off);
    k_zero<<<dim3(256), 256, 0, stream>>>((float*)cur, NN2);
    k_fill_csr<<<dim3(1024), 256, 0, stream>>>(d2, s2, NE2, e2off, cur, e2ids);

    // weight prep (hi/lo split, transposed)
    k_wembT<<<dim3(64), 256, 0, stream>>>(W_emb, wembT);
    for (int l = 0; l < NL; ++l) {
        k_wt<<<dim3(512), 256, 0, stream>>>(gw1 + (size_t)l * D * 2 * D, gw1T + (size_t)l * 2 * 2 * D * D, D, 2 * D);
        k_wt<<<dim3(512), 256, 0, stream>>>(gw2 + (size_t)l * 2 * D * D, gw2T + (size_t)l * 2 * 2 * D * D, 2 * D, D);
    }
    k_wt<<<dim3(256), 256, 0, stream>>>(i1wn, i1wnT, D, D);
    k_wt<<<dim3(256), 256, 0, stream>>>(i1ws, i1wsT, D, D);
    k_wt<<<dim3(256), 256, 0, stream>>>(i2wn, i2wnT, D, D);
    k_wt<<<dim3(256), 256, 0, stream>>>(i2ws, i2wsT, D, D);

    // atom embedding: HB(f32) = relu(x @ W_emb + b)
    k_xemb<<<ew, 256, 0, stream>>>(x, XEMB);
    k_mgemm<1,1,0,1,1><<<dim3(1, (NA + 127) / 128), 512, 0, stream>>>(
        XEMB, 64, wembT, b_emb, nullptr, nullptr, HB, D, NA, D, 64);

    // GIN stack
    for (int l = 0; l < NL; ++l) {
        k_gin_gather<<<sg, 256, 0, stream>>>(HB, eoff, eids, etab + (size_t)l * 4 * D, epsv, l, ZB);
        for (int c = 0; c < NA / CH; ++c) {
            k_mgemm<1,1,0,0,1><<<dim3(2, (CH + 127) / 128), 512, 0, stream>>>(
                ZB + (size_t)c * CH * D, D, gw1T + (size_t)l * 2 * 2 * D * D,
                gb1 + (size_t)l * 2 * D, nullptr, nullptr, TC, 2 * D, CH, 2 * D, D);
            k_mgemm<1,0,0,1,1><<<dim3(1, (CH + 127) / 128), 512, 0, stream>>>(
                TC, 2 * D, gw2T + (size_t)l * 2 * 2 * D * D,
                gb2 + (size_t)l * D, nullptr, nullptr, HB + (size_t)c * CH * D, D, CH, D, 2 * D);
        }
        k_zero<<<dim3(1), 512, 0, stream>>>(BS, 512);
        k_bn_stats<<<dim3(512), 256, 0, stream>>>(HB, BS, BS + D, NA);
        k_bn_final<<<dim3(1), 256, 0, stream>>>(BS, BS + D, bng + (size_t)l * D, bnb + (size_t)l * D, SC, SH, NA);
        k_bn_apply<<<ew, 256, 0, stream>>>(HB, SC, SH, (size_t)NA * D, l < NL - 1 ? 1 : 0);
    }

    // x_1 pooling
    k_pool1<<<dim3(NG), 256, 0, stream>>>(HB, gst, Mb);

    // xp = segment_mean(HB[a0], a1) -> XPB (bf16)
    k_xp_gather<<<sg, 256, 0, stream>>>(HB, aoff, aids, XPB);
    // HB dead

    // GraphConv 1: HN = xcat@wn (+iso tail); SELF = xcat@ws + b (+iso tail), in place; gather+relu
    k_mgemm<0,0,1,0,0><<<dim3(1, (NN2 + 127) / 128), 512, 0, stream>>>(
        XPB, D, i1wnT, nullptr, iso, i1wn + (size_t)D * D, HN, D, NN2, D, D);
    k_mgemm<1,0,1,0,0><<<dim3(1, (NN2 + 127) / 128), 512, 0, stream>>>(
        XPB, D, i1wsT, i1b, iso, i1ws + (size_t)D * D, XPB, D, NN2, D, D);
    k_conv_gather<0><<<sg, 256, 0, stream>>>(XPB, HN, e2off, e2ids, nullptr, nullptr);

    // GraphConv 2
    k_mgemm<0,0,0,0,0><<<dim3(1, (NN2 + 127) / 128), 512, 0, stream>>>(
        XPB, D, i2wnT, nullptr, nullptr, nullptr, HN, D, NN2, D, D);
    k_mgemm<1,0,0,0,0><<<dim3(1, (NN2 + 127) / 128), 512, 0, stream>>>(
        XPB, D, i2wsT, i2b, nullptr, nullptr, XPB, D, NN2, D, D);
    k_conv_gather<1><<<sg, 256, 0, stream>>>(XPB, HN, e2off, e2ids, batch2, Mb);
    k_div2<<<dim3(NG), 256, 0, stream>>>(Mb, g2st);

    // FC head (f32)
    k_gemm<<<ggrid(NG, D), 256, 0, stream>>>(Mb, 2 * D, fc0w, D, fc0b, F1, D, NG, D, 2 * D, 1);
    k_gemm<<<ggrid(NG, D / 2), 256, 0, stream>>>(F1, D, fc1w, D / 2, fc1b, F2, D / 2, NG, D / 2, D, 1);
    k_gemm<<<ggrid(NG, D / 4), 256, 0, stream>>>(F2, D / 2, fc2w, D / 4, fc2b, F3, D / 4, NG, D / 4, D / 2, 1);
    k_last<<<dim3((NG + 3) / 4), 256, 0, stream>>>(F3, lw, lb, out, NG);
}

// Round 7
// 3269.511 us; speedup vs baseline: 4.6844x; 1.1954x over previous
//
#include <hip/hip_runtime.h>
#include <cstddef>

// ---------------- problem constants ----------------
constexpr int NA   = 100000;
constexpr int NE   = 200000;
constexpr int NN2  = 200000;
constexpr int NASS = 400000;
constexpr int NE2  = 400000;
constexpr int NG   = 5000;
constexpr int D    = 256;
constexpr int FEAT = 40;
constexpr int NI2  = 8;
constexpr int NL   = 5;
constexpr int CH   = 25000;   // GIN hidden chunk rows (NA = 4*CH)

typedef unsigned short u16;
typedef __attribute__((ext_vector_type(8))) short bf16x8;
typedef __attribute__((ext_vector_type(4))) float f32x4;

static __device__ __forceinline__ float b2f(u16 s) {
    union { unsigned int u; float f; } v; v.u = ((unsigned int)s) << 16; return v.f;
}
static __device__ __forceinline__ u16 f2b(float f) {
    union { unsigned int u; float f; } v; v.f = f;
    unsigned int r = v.u + 0x7FFFu + ((v.u >> 16) & 1u);
    return (u16)(r >> 16);
}

// ---------------- workspace layout (byte offsets); ws_size = 240 MiB ----------------
// GIN:  ZB bf16[NA,256]@0 | TC hi/lo bf16[CH,512]x2 @51.2M | HB hi@102.4M lo@153.6M bf16[NA,256]
//       (HB hi holds post-BN h after bn_apply; lo holds z residual, dead after apply)
// emb:  XEMB hi/lo bf16[NA,64]x2 @51.2M (dead before TC)
// conv: XPB bf16[NN2,256]@0 (over ZB+TC) | HN bf16[NN2,256]@102.4M (over dead HB planes)
constexpr size_t ZB_OFF   = 0;
constexpr size_t TC_OFF   = 51200000;
constexpr size_t XEMB_OFF = 51200000;
constexpr size_t HB_OFF   = 102400000;   // hi plane; lo plane at +NA*D elems (@153.6M)
constexpr size_t XPB_OFF  = 0;
constexpr size_t HN_OFF   = 102400000;
// tail
constexpr size_t MB_OFF   = 204800000;   // f32 [NG,512]
constexpr size_t F1_OFF   = 215040000;   // f32 [NG,256] (also CSR pack scratch)
constexpr size_t F2_OFF   = 220160000;
constexpr size_t F3_OFF   = 222720000;
constexpr size_t WEMT_OFF = 224000000;   // bf16 2 planes [256][64]
constexpr size_t GW1T_OFF = 224065536;   // bf16 5 x 2 planes [512][256]
constexpr size_t GW2T_OFF = 226686976;   // bf16 5 x 2 planes [256][512]
constexpr size_t IWT_OFF  = 229308416;   // bf16 4 weights x 2 planes [256][256]
constexpr size_t EOFF_OFF = 230400000;   // int [NA+1]
constexpr size_t EIDS_OFF = 230800768;   // int [NE] packed src<<2|attr
constexpr size_t AOFF_OFF = 231600832;   // int [NN2+1]
constexpr size_t AIDS_OFF = 232400896;   // int [NASS]
constexpr size_t E2OFF_OFF= 234000960;   // int [NN2+1]
constexpr size_t E2IDS_OFF= 234801024;   // int [NE2]
constexpr size_t CUR_OFF  = 236401088;   // int [NN2]
constexpr size_t PART_OFF = 237201152;   // int [256]
constexpr size_t GST_OFF  = 237202240;   // int [NG+1]
constexpr size_t G2ST_OFF = 237222272;   // int [NG+1]
constexpr size_t BS_OFF   = 237242304;   // f32 [512]
constexpr size_t SCL_OFF  = 237244416;   // f32 [NL][256] bn scale
constexpr size_t SHL_OFF  = 237249536;   // f32 [NL][256] bn shift
constexpr size_t WS_BYTES = 237254656;

// ---------------- MFMA bf16 GEMM, split hi/lo operands ----------------
// C[M,N] = (Ah[+Al]) @ (Bh+Bl)^T [+bias] [+iso@wtail] [relu]
// A bf16 [M][lda], lo plane at A+M*lda (ALO). Bt [N][K] hi, lo at +N*K.
// CSPLIT: write hi at C, lo at C+clo (clo = element offset of lo plane).
// BM=128, BN=256 (grid.x=N/256 exact), BK=32, 512 thr = 8 waves (2x4 of 64x64).
template<int BIAS, int RELU, int ISO, int ALO, int CSPLIT>
__global__ __launch_bounds__(512) void k_mgemm(
    const u16* __restrict__ A, int lda,
    const u16* __restrict__ Bt,
    const float* __restrict__ bias,
    const float* __restrict__ iso,   // [M][8] f32 (ISO)
    const float* __restrict__ wtail, // [8][256] f32 (ISO; N==256)
    u16* __restrict__ C, int ldc, long clo,
    int M, int N, int K)
{
    __shared__ __align__(16) u16 Ah[128][40];
    __shared__ __align__(16) u16 Al[ALO ? 128 : 1][40];
    __shared__ __align__(16) u16 Bh[256][40];
    __shared__ __align__(16) u16 Bl[256][40];
    const int tid = threadIdx.x;
    const int wave = tid >> 6, lane = tid & 63;
    const int wr = wave >> 2, wc = wave & 3;
    const int bm = blockIdx.y * 128, bn = blockIdx.x * 256;
    const int l15 = lane & 15, lhi = lane >> 4;
    const int ar = tid >> 2, ac = (tid & 3) << 3;
    const u16* Alo = A + (size_t)M * lda;
    const u16* Blo = Bt + (size_t)N * K;
    f32x4 acc[4][4] = {};
    const int ktiles = K >> 5;
    for (int kt = 0; kt < ktiles; ++kt) {
        const int k0 = kt << 5;
        uint4 avh = {0,0,0,0}, avl = {0,0,0,0};
        if (bm + ar < M) {
            avh = *(const uint4*)(A + (size_t)(bm + ar) * lda + k0 + ac);
            if (ALO) avl = *(const uint4*)(Alo + (size_t)(bm + ar) * lda + k0 + ac);
        }
        uint4 b0h = *(const uint4*)(Bt  + (size_t)(bn + ar) * K + k0 + ac);
        uint4 b1h = *(const uint4*)(Bt  + (size_t)(bn + 128 + ar) * K + k0 + ac);
        uint4 b0l = *(const uint4*)(Blo + (size_t)(bn + ar) * K + k0 + ac);
        uint4 b1l = *(const uint4*)(Blo + (size_t)(bn + 128 + ar) * K + k0 + ac);
        __syncthreads();
        *(uint4*)&Ah[ar][ac] = avh;
        if (ALO) *(uint4*)&Al[ar][ac] = avl;
        *(uint4*)&Bh[ar][ac] = b0h;  *(uint4*)&Bh[128 + ar][ac] = b1h;
        *(uint4*)&Bl[ar][ac] = b0l;  *(uint4*)&Bl[128 + ar][ac] = b1l;
        __syncthreads();
        bf16x8 fah[4], fal[4], fbh[4], fbl[4];
        #pragma unroll
        for (int m = 0; m < 4; ++m) {
            fah[m] = *(const bf16x8*)&Ah[wr * 64 + m * 16 + l15][lhi * 8];
            if (ALO) fal[m] = *(const bf16x8*)&Al[wr * 64 + m * 16 + l15][lhi * 8];
        }
        #pragma unroll
        for (int n = 0; n < 4; ++n) {
            fbh[n] = *(const bf16x8*)&Bh[wc * 64 + n * 16 + l15][lhi * 8];
            fbl[n] = *(const bf16x8*)&Bl[wc * 64 + n * 16 + l15][lhi * 8];
        }
        #pragma unroll
        for (int m = 0; m < 4; ++m)
            #pragma unroll
            for (int n = 0; n < 4; ++n) {
                acc[m][n] = __builtin_amdgcn_mfma_f32_16x16x32_bf16(fah[m], fbh[n], acc[m][n], 0, 0, 0);
                acc[m][n] = __builtin_amdgcn_mfma_f32_16x16x32_bf16(fah[m], fbl[n], acc[m][n], 0, 0, 0);
                if (ALO)
                    acc[m][n] = __builtin_amdgcn_mfma_f32_16x16x32_bf16(fal[m], fbh[n], acc[m][n], 0, 0, 0);
            }
    }
    // epilogue: C/D layout col=lane&15, row=(lane>>4)*4+reg [m89-verified]
    #pragma unroll
    for (int m = 0; m < 4; ++m) {
        int rbase = bm + wr * 64 + m * 16 + lhi * 4;
        #pragma unroll
        for (int n = 0; n < 4; ++n) {
            int col = bn + wc * 64 + n * 16 + l15;
            #pragma unroll
            for (int r = 0; r < 4; ++r) {
                int row = rbase + r;
                if (row >= M) continue;
                float v = acc[m][n][r];
                if (BIAS) v += bias[col];
                if (ISO) {
                    const float* ir = iso + (size_t)row * NI2;
                    #pragma unroll
                    for (int k = 0; k < NI2; ++k) v += ir[k] * wtail[k * 256 + col];
                }
                if (RELU) v = fmaxf(v, 0.f);
                size_t cidx = (size_t)row * ldc + col;
                if (CSPLIT) {
                    u16 h = f2b(v);
                    C[cidx] = h;
                    C[cidx + clo] = f2b(v - b2f(h));
                } else {
                    C[cidx] = f2b(v);
                }
            }
        }
    }
}

// ---------------- fp32 tiled GEMM (FC head only) ----------------
__global__ __launch_bounds__(256) void k_gemm(
    const float* __restrict__ A, int lda,
    const float* __restrict__ B, int ldb,
    const float* __restrict__ bias,
    float* __restrict__ C, int ldc,
    int M, int N, int K, int relu)
{
    __shared__ __align__(16) float As[16][68];
    __shared__ __align__(16) float Bs[16][68];
    const int tid = threadIdx.x;
    const int tx = tid & 15, ty = tid >> 4;
    const int bm = blockIdx.y * 64, bn = blockIdx.x * 64;
    const int arow = tid >> 2, akq = (tid & 3) << 2;
    const int bk = tid >> 4, bnq = (tid & 15) << 2;
    float c[4][4] = {};
    const int ktiles = (K + 15) >> 4;
    for (int kt = 0; kt < ktiles; ++kt) {
        const int k0 = kt << 4;
        float4 av = make_float4(0.f, 0.f, 0.f, 0.f);
        if (bm + arow < M && k0 + akq + 4 <= K)
            av = *reinterpret_cast<const float4*>(A + (size_t)(bm + arow) * lda + (k0 + akq));
        As[akq + 0][arow] = av.x; As[akq + 1][arow] = av.y;
        As[akq + 2][arow] = av.z; As[akq + 3][arow] = av.w;
        float4 bv = make_float4(0.f, 0.f, 0.f, 0.f);
        if (k0 + bk < K && bn + bnq + 4 <= N)
            bv = *reinterpret_cast<const float4*>(B + (size_t)(k0 + bk) * ldb + (bn + bnq));
        *reinterpret_cast<float4*>(&Bs[bk][bnq]) = bv;
        __syncthreads();
        #pragma unroll
        for (int k = 0; k < 16; ++k) {
            float a0 = As[k][ty*4+0], a1 = As[k][ty*4+1], a2 = As[k][ty*4+2], a3 = As[k][ty*4+3];
            float b0 = Bs[k][tx*4+0], b1 = Bs[k][tx*4+1], b2 = Bs[k][tx*4+2], b3 = Bs[k][tx*4+3];
            c[0][0]+=a0*b0;c[0][1]+=a0*b1;c[0][2]+=a0*b2;c[0][3]+=a0*b3;
            c[1][0]+=a1*b0;c[1][1]+=a1*b1;c[1][2]+=a1*b2;c[1][3]+=a1*b3;
            c[2][0]+=a2*b0;c[2][1]+=a2*b1;c[2][2]+=a2*b2;c[2][3]+=a2*b3;
            c[3][0]+=a3*b0;c[3][1]+=a3*b1;c[3][2]+=a3*b2;c[3][3]+=a3*b3;
        }
        __syncthreads();
    }
    #pragma unroll
    for (int i = 0; i < 4; ++i) {
        int row = bm + ty * 4 + i;
        if (row >= M) continue;
        #pragma unroll
        for (int j = 0; j < 4; ++j) {
            int col = bn + tx * 4 + j;
            if (col >= N) continue;
            float v = c[i][j] + bias[col];
            if (relu) v = fmaxf(v, 0.f);
            C[(size_t)row * ldc + col] = v;
        }
    }
}

// ---------------- utility ----------------
__global__ void k_zero(float* __restrict__ p, size_t n) {
    size_t i = (size_t)blockIdx.x * blockDim.x + threadIdx.x;
    size_t st = (size_t)gridDim.x * blockDim.x;
    for (; i < n; i += st) p[i] = 0.f;
}
__global__ void k_fill(float* __restrict__ p, int n, float v) {
    int i = blockIdx.x * blockDim.x + threadIdx.x;
    int st = gridDim.x * blockDim.x;
    for (; i < n; i += st) p[i] = v;
}

// ---------------- CSR build ----------------
__global__ void k_count(const int* __restrict__ idx, int n, int* __restrict__ cnt) {
    int i = blockIdx.x * blockDim.x + threadIdx.x;
    int st = gridDim.x * blockDim.x;
    for (; i < n; i += st) atomicAdd(&cnt[idx[i]], 1);
}
__global__ void k_scan_partial(const int* __restrict__ cnt, int n, int* __restrict__ part) {
    __shared__ int sm[256];
    int c = blockIdx.x, t = threadIdx.x;
    int base = c * 4096 + t * 16;
    int s = 0;
    #pragma unroll
    for (int j = 0; j < 16; ++j) { int i = base + j; if (i < n) s += cnt[i]; }
    sm[t] = s; __syncthreads();
    for (int o = 128; o; o >>= 1) { if (t < o) sm[t] += sm[t + o]; __syncthreads(); }
    if (t == 0) part[c] = sm[0];
}
__global__ void k_scan_mid(int* __restrict__ part, int nch, int* __restrict__ off, int n) {
    if (threadIdx.x == 0 && blockIdx.x == 0) {
        int run = 0;
        for (int c = 0; c < nch; ++c) { int v = part[c]; part[c] = run; run += v; }
        off[n] = run;
    }
}
__global__ void k_scan_final(const int* __restrict__ cnt, int n, const int* __restrict__ part,
                             int* __restrict__ off) {
    __shared__ int sm[256];
    int c = blockIdx.x, t = threadIdx.x;
    int base = c * 4096 + t * 16;
    int loc[16]; int s = 0;
    #pragma unroll
    for (int j = 0; j < 16; ++j) { int i = base + j; int v = (i < n) ? cnt[i] : 0; loc[j] = s; s += v; }
    sm[t] = s; __syncthreads();
    for (int o = 1; o < 256; o <<= 1) {
        int v = (t >= o) ? sm[t - o] : 0;
        __syncthreads(); sm[t] += v; __syncthreads();
    }
    int tpre = (t == 0) ? 0 : sm[t - 1];
    int cb = part[c];
    #pragma unroll
    for (int j = 0; j < 16; ++j) { int i = base + j; if (i < n) off[i] = cb + tpre + loc[j]; }
}
__global__ void k_fill_csr(const int* __restrict__ idx, const int* __restrict__ pay, int n,
                           const int* __restrict__ off, int* __restrict__ cur, int* __restrict__ ids) {
    int i = blockIdx.x * blockDim.x + threadIdx.x;
    int st = gridDim.x * blockDim.x;
    for (; i < n; i += st) {
        int d = idx[i];
        int p = off[d] + atomicAdd(&cur[d], 1);
        ids[p] = pay[i];
    }
}
__global__ void k_pack(const int* __restrict__ src, const int* __restrict__ attr,
                       int* __restrict__ pk, int n) {
    int i = blockIdx.x * blockDim.x + threadIdx.x;
    int st = gridDim.x * blockDim.x;
    for (; i < n; i += st) pk[i] = (src[i] << 2) | attr[i];
}
__global__ void k_lbound(const int* __restrict__ arr, int n, int nseg, int* __restrict__ st) {
    int g = blockIdx.x * blockDim.x + threadIdx.x;
    if (g > nseg) return;
    int lo = 0, hi = n;
    while (lo < hi) { int mid = (lo + hi) >> 1; if (arr[mid] < g) lo = mid + 1; else hi = mid; }
    st[g] = lo;
}

// ---------------- weight / input prep (hi+lo split planes) ----------------
__global__ void k_wt(const float* __restrict__ w, u16* __restrict__ wt, int K, int N) {
    int i = blockIdx.x * blockDim.x + threadIdx.x;
    int tot = K * N, st = gridDim.x * blockDim.x;
    for (; i < tot; i += st) {
        int n_ = i / K, k = i - n_ * K;
        float v = w[(size_t)k * N + n_];
        u16 h = f2b(v);
        wt[i] = h;
        wt[(size_t)tot + i] = f2b(v - b2f(h));
    }
}
__global__ void k_wembT(const float* __restrict__ w, u16* __restrict__ wt) {
    int i = blockIdx.x * blockDim.x + threadIdx.x;
    if (i >= 256 * 64) return;
    int n_ = i >> 6, k = i & 63;
    float v = (k < FEAT) ? w[(size_t)k * 256 + n_] : 0.f;
    u16 h = f2b(v);
    wt[i] = h;
    wt[256 * 64 + i] = f2b(v - b2f(h));
}
__global__ void k_xemb(const float* __restrict__ x, u16* __restrict__ xe) {
    size_t i = (size_t)blockIdx.x * blockDim.x + threadIdx.x;
    size_t st = (size_t)gridDim.x * blockDim.x;
    size_t tot = (size_t)NA * 64;
    for (; i < tot; i += st) {
        int r = (int)(i >> 6), c = (int)(i & 63);
        float v = (c < FEAT) ? x[(size_t)r * FEAT + c] : 0.f;
        u16 h = f2b(v);
        xe[i] = h;
        xe[tot + i] = f2b(v - b2f(h));
    }
}

// ---------------- CSR gathers (read post-BN h, bf16) ----------------
// ZB[v] = bf16((1+eps)*h[v] + sum_e(h[src] + etab[attr]))
__global__ void k_gin_gather(const u16* __restrict__ hb, const int* __restrict__ off,
                             const int* __restrict__ ids, const float* __restrict__ etab_l,
                             const float* __restrict__ epsv, int l, u16* __restrict__ zb) {
    int wid = (blockIdx.x * blockDim.x + threadIdx.x) >> 6;
    int lane = threadIdx.x & 63;
    int nw = (gridDim.x * blockDim.x) >> 6;
    int c = lane * 4;
    float e1 = 1.f + epsv[l];
    for (int v = wid; v < NA; v += nw) {
        ushort4 h = *(const ushort4*)(hb + (size_t)v * D + c);
        float s0 = e1 * b2f(h.x), s1 = e1 * b2f(h.y), s2 = e1 * b2f(h.z), s3 = e1 * b2f(h.w);
        int p1 = off[v + 1];
        for (int p = off[v]; p < p1; ++p) {
            int pk = ids[p]; int src = pk >> 2; int at = pk & 3;
            ushort4 u = *(const ushort4*)(hb + (size_t)src * D + c);
            float4 t = *(const float4*)(etab_l + at * D + c);
            s0 += b2f(u.x) + t.x; s1 += b2f(u.y) + t.y;
            s2 += b2f(u.z) + t.z; s3 += b2f(u.w) + t.w;
        }
        ushort4 o; o.x = f2b(s0); o.y = f2b(s1); o.z = f2b(s2); o.w = f2b(s3);
        *(ushort4*)(zb + (size_t)v * D + c) = o;
    }
}
// XPB[v] = bf16(mean(h rows))
__global__ void k_xp_gather(const u16* __restrict__ hb, const int* __restrict__ off,
                            const int* __restrict__ ids, u16* __restrict__ xpb) {
    int wid = (blockIdx.x * blockDim.x + threadIdx.x) >> 6;
    int lane = threadIdx.x & 63;
    int nw = (gridDim.x * blockDim.x) >> 6;
    int c = lane * 4;
    for (int v = wid; v < NN2; v += nw) {
        int p0 = off[v], p1 = off[v + 1];
        float s0 = 0, s1 = 0, s2 = 0, s3 = 0;
        for (int p = p0; p < p1; ++p) {
            ushort4 u = *(const ushort4*)(hb + (size_t)ids[p] * D + c);
            s0 += b2f(u.x); s1 += b2f(u.y); s2 += b2f(u.z); s3 += b2f(u.w);
        }
        float inv = 1.f / fmaxf((float)(p1 - p0), 1.f);
        ushort4 o;
        o.x = f2b(s0 * inv); o.y = f2b(s1 * inv); o.z = f2b(s2 * inv); o.w = f2b(s3 * inv);
        *(ushort4*)(xpb + (size_t)v * D + c) = o;
    }
}
// SELF[v] = bf16(relu(SELF[v] + sum HN[nbr]))  in place
__global__ void k_conv_gather(u16* __restrict__ selfb, const u16* __restrict__ hn,
                              const int* __restrict__ off, const int* __restrict__ ids) {
    int wid = (blockIdx.x * blockDim.x + threadIdx.x) >> 6;
    int lane = threadIdx.x & 63;
    int nw = (gridDim.x * blockDim.x) >> 6;
    int c = lane * 4;
    for (int v = wid; v < NN2; v += nw) {
        ushort4 sv = *(const ushort4*)(selfb + (size_t)v * D + c);
        float s0 = b2f(sv.x), s1 = b2f(sv.y), s2 = b2f(sv.z), s3 = b2f(sv.w);
        int p1 = off[v + 1];
        for (int p = off[v]; p < p1; ++p) {
            ushort4 u = *(const ushort4*)(hn + (size_t)ids[p] * D + c);
            s0 += b2f(u.x); s1 += b2f(u.y); s2 += b2f(u.z); s3 += b2f(u.w);
        }
        ushort4 o;
        o.x = f2b(fmaxf(s0, 0.f)); o.y = f2b(fmaxf(s1, 0.f));
        o.z = f2b(fmaxf(s2, 0.f)); o.w = f2b(fmaxf(s3, 0.f));
        *(ushort4*)(selfb + (size_t)v * D + c) = o;
    }
}

// ---------------- BN (stats on split z = hi+lo; apply writes h into hi plane) ----------------
__global__ void k_bn_stats(const u16* __restrict__ zhi, const u16* __restrict__ zlo,
                           float* __restrict__ sum, float* __restrict__ sumsq, int n) {
    int c = threadIdx.x;
    float s = 0.f, q = 0.f;
    for (int r = blockIdx.x; r < n; r += gridDim.x) {
        float v = b2f(zhi[(size_t)r * D + c]) + b2f(zlo[(size_t)r * D + c]);
        s += v; q += v * v;
    }
    atomicAdd(&sum[c], s);
    atomicAdd(&sumsq[c], q);
}
__global__ void k_bn_final(const float* __restrict__ sum, const float* __restrict__ sumsq,
                           const float* __restrict__ gamma, const float* __restrict__ beta,
                           float* __restrict__ scale, float* __restrict__ shift, int n) {
    int c = threadIdx.x;
    float mu = sum[c] / (float)n;
    float var = sumsq[c] / (float)n - mu * mu;
    float sc = gamma[c] * rsqrtf(var + 1e-5f);
    scale[c] = sc;
    shift[c] = beta[c] - mu * sc;
}
// hi[i] = bf16(relu?(sc*(hi[i]+lo[i]) + sh))
__global__ void k_bn_apply(u16* __restrict__ zhi, const u16* __restrict__ zlo,
                           const float* __restrict__ scale, const float* __restrict__ shift,
                           size_t n, int relu) {
    size_t i = (size_t)blockIdx.x * blockDim.x + threadIdx.x;
    size_t st = (size_t)gridDim.x * blockDim.x;
    for (; i < n; i += st) {
        int c = (int)(i & (D - 1));
        float z = b2f(zhi[i]) + b2f(zlo[i]);
        float v = scale[c] * z + shift[c];
        if (relu) v = fmaxf(v, 0.f);
        zhi[i] = f2b(v);
    }
}

// ---------------- pooling / head ----------------
__global__ void k_pool1(const u16* __restrict__ hb, const int* __restrict__ gst,
                        float* __restrict__ mb) {
    int g = blockIdx.x, t = threadIdx.x;
    int a = gst[g], b = gst[g + 1];
    float s = 0.f;
    for (int r = a; r < b; ++r) s += b2f(hb[(size_t)r * D + t]);
    mb[(size_t)g * (2 * D) + t] = s / fmaxf((float)(b - a), 1.f);
}
__global__ void k_pool2(const u16* __restrict__ x2b, const int* __restrict__ g2st,
                        float* __restrict__ mb) {
    int g = blockIdx.x, t = threadIdx.x;
    int a = g2st[g], b = g2st[g + 1];
    float s = 0.f;
    for (int r = a; r < b; ++r) s += b2f(x2b[(size_t)r * D + t]);
    mb[(size_t)g * (2 * D) + D + t] = s / fmaxf((float)(b - a), 1.f);
}
__global__ void k_last(const float* __restrict__ f3, const float* __restrict__ w,
                       const float* __restrict__ b, float* __restrict__ out, int gn) {
    int g = blockIdx.x * 4 + (threadIdx.x >> 6);
    int lane = threadIdx.x & 63;
    if (g >= gn) return;
    float v = f3[(size_t)g * 64 + lane] * w[lane];
    #pragma unroll
    for (int off = 32; off; off >>= 1) v += __shfl_down(v, off);
    if (lane == 0) out[g] = v + b[0];
}

// ---------------- host ----------------
static inline dim3 ggrid(int M, int N) { return dim3((N + 63) / 64, (M + 63) / 64); }

extern "C" void kernel_launch(void* const* d_in, const int* in_sizes, int n_in,
                              void* d_out, int out_size, void* d_ws, size_t ws_size,
                              hipStream_t stream) {
    const float* x      = (const float*)d_in[0];
    const int*   eidx   = (const int*)  d_in[1];
    const int*   eattr  = (const int*)  d_in[2];
    const float* iso    = (const float*)d_in[3];
    const int*   eidx2  = (const int*)  d_in[4];
    const int*   assign = (const int*)  d_in[5];
    const int*   batch  = (const int*)  d_in[6];
    const int*   batch2 = (const int*)  d_in[7];
    const float* W_emb  = (const float*)d_in[8];
    const float* b_emb  = (const float*)d_in[9];
    const float* etab   = (const float*)d_in[10];
    const float* epsv   = (const float*)d_in[11];
    const float* gw1    = (const float*)d_in[12];
    const float* gb1    = (const float*)d_in[13];
    const float* gw2    = (const float*)d_in[14];
    const float* gb2    = (const float*)d_in[15];
    const float* bng    = (const float*)d_in[16];
    const float* bnb    = (const float*)d_in[17];
    const float* i1ws   = (const float*)d_in[18];
    const float* i1wn   = (const float*)d_in[19];
    const float* i1b    = (const float*)d_in[20];
    const float* i2ws   = (const float*)d_in[21];
    const float* i2wn   = (const float*)d_in[22];
    const float* i2b    = (const float*)d_in[23];
    const float* fc0w   = (const float*)d_in[24];
    const float* fc0b   = (const float*)d_in[25];
    const float* fc1w   = (const float*)d_in[26];
    const float* fc1b   = (const float*)d_in[27];
    const float* fc2w   = (const float*)d_in[28];
    const float* fc2b   = (const float*)d_in[29];
    const float* lw     = (const float*)d_in[30];
    const float* lb     = (const float*)d_in[31];

    float* out = (float*)d_out;
    char*  ws  = (char*)d_ws;
    if (ws_size < WS_BYTES) {
        k_fill<<<32, 256, 0, stream>>>(out, out_size, 10000.0f + (float)(ws_size >> 20));
        return;
    }

    u16*   ZB   = (u16*)(ws + ZB_OFF);
    u16*   TC   = (u16*)(ws + TC_OFF);    // hi plane; lo at +CH*512
    u16*   XEMB = (u16*)(ws + XEMB_OFF);  // hi plane; lo at +NA*64
    u16*   HB   = (u16*)(ws + HB_OFF);    // hi plane (z then h); lo at +NA*D
    u16*   XPB  = (u16*)(ws + XPB_OFF);   // xp -> conv self/out (in place)
    u16*   HN   = (u16*)(ws + HN_OFF);
    float* Mb   = (float*)(ws + MB_OFF);
    float* F1   = (float*)(ws + F1_OFF);
    float* F2   = (float*)(ws + F2_OFF);
    float* F3   = (float*)(ws + F3_OFF);
    u16*   wembT= (u16*)(ws + WEMT_OFF);
    u16*   gw1T = (u16*)(ws + GW1T_OFF);
    u16*   gw2T = (u16*)(ws + GW2T_OFF);
    u16*   iwT  = (u16*)(ws + IWT_OFF);
    u16*   i1wnT= iwT;
    u16*   i1wsT= iwT + 2 * 65536;
    u16*   i2wnT= iwT + 4 * 65536;
    u16*   i2wsT= iwT + 6 * 65536;
    int*   eoff = (int*)(ws + EOFF_OFF);
    int*   eids = (int*)(ws + EIDS_OFF);
    int*   aoff = (int*)(ws + AOFF_OFF);
    int*   aids = (int*)(ws + AIDS_OFF);
    int*   e2off= (int*)(ws + E2OFF_OFF);
    int*   e2ids= (int*)(ws + E2IDS_OFF);
    int*   cur  = (int*)(ws + CUR_OFF);
    int*   part = (int*)(ws + PART_OFF);
    int*   gst  = (int*)(ws + GST_OFF);
    int*   g2st = (int*)(ws + G2ST_OFF);
    float* BS   = (float*)(ws + BS_OFF);
    float* SCL  = (float*)(ws + SCL_OFF);
    float* SHL  = (float*)(ws + SHL_OFF);
    int*   packs= (int*)F1;   // scratch: F1 unused until head

    const int* e_src = eidx;   const int* e_dst = eidx + NE;
    const int* a0    = assign; const int* a1    = assign + NASS;
    const int* s2    = eidx2;  const int* d2    = eidx2 + NE2;

    u16* HBlo = HB + (size_t)NA * D;

    dim3 sg(2048);   // wave-stride gathers
    dim3 ew(8192);   // grid-stride elementwise
    const int nchA = (NA + 4095) / 4096;
    const int nch2 = (NN2 + 4095) / 4096;

    // pooling bounds (batch, batch_2 sorted)
    k_lbound<<<dim3((NG + 256) / 256), 256, 0, stream>>>(batch, NA, NG, gst);
    k_lbound<<<dim3((NG + 256) / 256), 256, 0, stream>>>(batch2, NN2, NG, g2st);

    // CSR: edges -> atoms
    k_zero<<<dim3(256), 256, 0, stream>>>((float*)cur, NA);
    k_count<<<dim3(1024), 256, 0, stream>>>(e_dst, NE, cur);
    k_scan_partial<<<dim3(nchA), 256, 0, stream>>>(cur, NA, part);
    k_scan_mid<<<dim3(1), 64, 0, stream>>>(part, nchA, eoff, NA);
    k_scan_final<<<dim3(nchA), 256, 0, stream>>>(cur, NA, part, eoff);
    k_zero<<<dim3(256), 256, 0, stream>>>((float*)cur, NA);
    k_pack<<<dim3(1024), 256, 0, stream>>>(e_src, eattr, packs, NE);
    k_fill_csr<<<dim3(1024), 256, 0, stream>>>(e_dst, packs, NE, eoff, cur, eids);

    // CSR: assignments -> 2-sets
    k_zero<<<dim3(256), 256, 0, stream>>>((float*)cur, NN2);
    k_count<<<dim3(1024), 256, 0, stream>>>(a1, NASS, cur);
    k_scan_partial<<<dim3(nch2), 256, 0, stream>>>(cur, NN2, part);
    k_scan_mid<<<dim3(1), 64, 0, stream>>>(part, nch2, aoff, NN2);
    k_scan_final<<<dim3(nch2), 256, 0, stream>>>(cur, NN2, part, aoff);
    k_zero<<<dim3(256), 256, 0, stream>>>((float*)cur, NN2);
    k_fill_csr<<<dim3(1024), 256, 0, stream>>>(a1, a0, NASS, aoff, cur, aids);

    // CSR: 2-set edges
    k_zero<<<dim3(256), 256, 0, stream>>>((float*)cur, NN2);
    k_count<<<dim3(1024), 256, 0, stream>>>(d2, NE2, cur);
    k_scan_partial<<<dim3(nch2), 256, 0, stream>>>(cur, NN2, part);
    k_scan_mid<<<dim3(1), 64, 0, stream>>>(part, nch2, e2off, NN2);
    k_scan_final<<<dim3(nch2), 256, 0, stream>>>(cur, NN2, part, e2off);
    k_zero<<<dim3(256), 256, 0, stream>>>((float*)cur, NN2);
    k_fill_csr<<<dim3(1024), 256, 0, stream>>>(d2, s2, NE2, e2off, cur, e2ids);

    // weight prep (hi/lo split, transposed [N][K])
    k_wembT<<<dim3(64), 256, 0, stream>>>(W_emb, wembT);
    for (int l = 0; l < NL; ++l) {
        k_wt<<<dim3(512), 256, 0, stream>>>(gw1 + (size_t)l * D * 2 * D, gw1T + (size_t)l * 2 * 2 * D * D, D, 2 * D);
        k_wt<<<dim3(512), 256, 0, stream>>>(gw2 + (size_t)l * 2 * D * D, gw2T + (size_t)l * 2 * 2 * D * D, 2 * D, D);
    }
    k_wt<<<dim3(256), 256, 0, stream>>>(i1wn, i1wnT, D, D);
    k_wt<<<dim3(256), 256, 0, stream>>>(i1ws, i1wsT, D, D);
    k_wt<<<dim3(256), 256, 0, stream>>>(i2wn, i2wnT, D, D);
    k_wt<<<dim3(256), 256, 0, stream>>>(i2ws, i2wsT, D, D);

    // atom embedding: HB(hi) = bf16(relu(x @ W_emb + b))   (post-activation, single plane)
    k_xemb<<<ew, 256, 0, stream>>>(x, XEMB);
    k_mgemm<1,1,0,1,0><<<dim3(1, (NA + 127) / 128), 512, 0, stream>>>(
        XEMB, 64, wembT, b_emb, nullptr, nullptr, HB, D, 0, NA, D, 64);

    // GIN stack: gather(h) -> MLP (z split hi/lo) -> bn stats/final -> apply (h into hi plane)
    for (int l = 0; l < NL; ++l) {
        k_gin_gather<<<sg, 256, 0, stream>>>(HB, eoff, eids, etab + (size_t)l * 4 * D, epsv, l, ZB);
        for (int c = 0; c < NA / CH; ++c) {
            k_mgemm<1,1,0,0,1><<<dim3(2, (CH + 127) / 128), 512, 0, stream>>>(
                ZB + (size_t)c * CH * D, D, gw1T + (size_t)l * 2 * 2 * D * D,
                gb1 + (size_t)l * 2 * D, nullptr, nullptr,
                TC, 2 * D, (long)CH * 2 * D, CH, 2 * D, D);
            k_mgemm<1,0,0,1,1><<<dim3(1, (CH + 127) / 128), 512, 0, stream>>>(
                TC, 2 * D, gw2T + (size_t)l * 2 * 2 * D * D,
                gb2 + (size_t)l * D, nullptr, nullptr,
                HB + (size_t)c * CH * D, D, (long)NA * D, CH, D, 2 * D);
        }
        k_zero<<<dim3(1), 512, 0, stream>>>(BS, 512);
        k_bn_stats<<<dim3(512), 256, 0, stream>>>(HB, HBlo, BS, BS + D, NA);
        k_bn_final<<<dim3(1), 256, 0, stream>>>(BS, BS + D, bng + (size_t)l * D, bnb + (size_t)l * D,
                                                SCL + l * D, SHL + l * D, NA);
        k_bn_apply<<<ew, 256, 0, stream>>>(HB, HBlo, SCL + l * D, SHL + l * D,
                                           (size_t)NA * D, l < NL - 1 ? 1 : 0);
    }

    // x_1 pooling (h in hi plane)
    k_pool1<<<dim3(NG), 256, 0, stream>>>(HB, gst, Mb);

    // xp = segment_mean(h[a0], a1) -> XPB bf16
    k_xp_gather<<<sg, 256, 0, stream>>>(HB, aoff, aids, XPB);
    // HB dead

    // GraphConv 1: HN = xcat@wn (+iso tail); SELF = xcat@ws + b (+iso tail) in place; gather+relu
    k_mgemm<0,0,1,0,0><<<dim3(1, (NN2 + 127) / 128), 512, 0, stream>>>(
        XPB, D, i1wnT, nullptr, iso, i1wn + (size_t)D * D, HN, D, 0, NN2, D, D);
    k_mgemm<1,0,1,0,0><<<dim3(1, (NN2 + 127) / 128), 512, 0, stream>>>(
        XPB, D, i1wsT, i1b, iso, i1ws + (size_t)D * D, XPB, D, 0, NN2, D, D);
    k_conv_gather<<<sg, 256, 0, stream>>>(XPB, HN, e2off, e2ids);

    // GraphConv 2
    k_mgemm<0,0,0,0,0><<<dim3(1, (NN2 + 127) / 128), 512, 0, stream>>>(
        XPB, D, i2wnT, nullptr, nullptr, nullptr, HN, D, 0, NN2, D, D);
    k_mgemm<1,0,0,0,0><<<dim3(1, (NN2 + 127) / 128), 512, 0, stream>>>(
        XPB, D, i2wsT, i2b, nullptr, nullptr, XPB, D, 0, NN2, D, D);
    k_conv_gather<<<sg, 256, 0, stream>>>(XPB, HN, e2off, e2ids);

    // x_2 pooling (sorted batch_2, no atomics)
    k_pool2<<<dim3(NG), 256, 0, stream>>>(XPB, g2st, Mb);

    // FC head (f32)
    k_gemm<<<ggrid(NG, D), 256, 0, stream>>>(Mb, 2 * D, fc0w, D, fc0b, F1, D, NG, D, 2 * D, 1);
    k_gemm<<<ggrid(NG, D / 2), 256, 0, stream>>>(F1, D, fc1w, D / 2, fc1b, F2, D / 2, NG, D / 2, D, 1);
    k_gemm<<<ggrid(NG, D / 4), 256, 0, stream>>>(F2, D / 2, fc2w, D / 4, fc2b, F3, D / 4, NG, D / 4, D / 2, 1);
    k_last<<<dim3((NG + 3) / 4), 256, 0, stream>>>(F3, lw, lb, out, NG);
}